// Round 1
// baseline (2885.009 us; speedup 1.0000x reference)
//
#include <hip/hip_runtime.h>

#define BATCH 4
#define CH 512
#define NSP 4096   // 64*64 spatial
#define TS 64
#define KT 64

// ---------------------------------------------------------------------------
// Generic pieces: every GEMM uses As[m][k] (64x65) and Bs[k][n] (64x65) tiles,
// 256 threads, each thread computes a 4x4 micro-tile at (ty+16i, tx+16j).
// Global loads are coalesced rows of 64 contiguous floats; LDS stores are
// either row-contiguous or stride-65 (conflict-free).
// ---------------------------------------------------------------------------

// K1: L[b][c][d] = sum_n x[b,c,n] * xflat[b, n*C + d]
__global__ __launch_bounds__(256) void k1_logits(const float* __restrict__ X,
                                                 float* __restrict__ Lg) {
    __shared__ float As[TS][KT + 1];
    __shared__ float Bs[KT][TS + 1];
    const int b = blockIdx.z;
    const float* base = X + (size_t)b * CH * NSP;
    const int c0 = blockIdx.y * TS, d0 = blockIdx.x * TS;
    const int tid = threadIdx.x;
    const int tx = tid & 15, ty = tid >> 4;
    const int lane = tid & 63, lrow = tid >> 6;
    float acc[4][4] = {};
    for (int k0 = 0; k0 < NSP; k0 += KT) {
#pragma unroll
        for (int r = 0; r < 16; r++) {
            int row = lrow + 4 * r;
            As[row][lane] = base[(size_t)(c0 + row) * NSP + k0 + lane]; // A(c,n) contiguous n
            Bs[row][lane] = base[(size_t)(k0 + row) * CH + d0 + lane];  // B(n,d) contiguous d
        }
        __syncthreads();
#pragma unroll
        for (int k = 0; k < KT; k++) {
            float a[4], bv[4];
#pragma unroll
            for (int i = 0; i < 4; i++) a[i] = As[ty + 16 * i][k];
#pragma unroll
            for (int j = 0; j < 4; j++) bv[j] = Bs[k][tx + 16 * j];
#pragma unroll
            for (int i = 0; i < 4; i++)
#pragma unroll
                for (int j = 0; j < 4; j++) acc[i][j] += a[i] * bv[j];
        }
        __syncthreads();
    }
    float* Lb = Lg + (size_t)b * CH * CH;
#pragma unroll
    for (int i = 0; i < 4; i++)
#pragma unroll
        for (int j = 0; j < 4; j++)
            Lb[(size_t)(c0 + ty + 16 * i) * CH + d0 + tx + 16 * j] = acc[i][j];
}

// Row softmax, in-place; one block of 256 per row, row length <= 4096.
__global__ __launch_bounds__(256) void softmax_rows(float* __restrict__ data, int len) {
    __shared__ float buf[4096];
    __shared__ float red[256];
    const int tid = threadIdx.x;
    float* row = data + (size_t)blockIdx.x * len;
    float m = -INFINITY;
    for (int i = tid; i < len; i += 256) {
        float v = row[i];
        buf[i] = v;
        m = fmaxf(m, v);
    }
    red[tid] = m;
    __syncthreads();
    for (int s = 128; s > 0; s >>= 1) {
        if (tid < s) red[tid] = fmaxf(red[tid], red[tid + s]);
        __syncthreads();
    }
    m = red[0];
    __syncthreads();  // everyone reads red[0] before it is overwritten below
    float sum = 0.f;
    for (int i = tid; i < len; i += 256) {
        float e = expf(buf[i] - m);
        buf[i] = e;
        sum += e;
    }
    red[tid] = sum;
    __syncthreads();
    for (int s = 128; s > 0; s >>= 1) {
        if (tid < s) red[tid] += red[tid + s];
        __syncthreads();
    }
    float inv = 1.0f / red[0];
    for (int i = tid; i < len; i += 256) row[i] = buf[i] * inv;
}

// K3: y[b][c][n] = sum_d A[b][c][d] * x[b][d][n] + x[b][c][n]
__global__ __launch_bounds__(256) void k3_out1(const float* __restrict__ Att,
                                               const float* __restrict__ X,
                                               float* __restrict__ Y) {
    __shared__ float As[TS][KT + 1];
    __shared__ float Bs[KT][TS + 1];
    const int b = blockIdx.z;
    const float* Ab = Att + (size_t)b * CH * CH;
    const float* Xb = X + (size_t)b * CH * NSP;
    const int c0 = blockIdx.y * TS, n0 = blockIdx.x * TS;
    const int tid = threadIdx.x;
    const int tx = tid & 15, ty = tid >> 4;
    const int lane = tid & 63, lrow = tid >> 6;
    float acc[4][4] = {};
    for (int k0 = 0; k0 < CH; k0 += KT) {
#pragma unroll
        for (int r = 0; r < 16; r++) {
            int row = lrow + 4 * r;
            As[row][lane] = Ab[(size_t)(c0 + row) * CH + k0 + lane];   // A(c,d) contiguous d
            Bs[row][lane] = Xb[(size_t)(k0 + row) * NSP + n0 + lane];  // B(d,n) contiguous n
        }
        __syncthreads();
#pragma unroll
        for (int k = 0; k < KT; k++) {
            float a[4], bv[4];
#pragma unroll
            for (int i = 0; i < 4; i++) a[i] = As[ty + 16 * i][k];
#pragma unroll
            for (int j = 0; j < 4; j++) bv[j] = Bs[k][tx + 16 * j];
#pragma unroll
            for (int i = 0; i < 4; i++)
#pragma unroll
                for (int j = 0; j < 4; j++) acc[i][j] += a[i] * bv[j];
        }
        __syncthreads();
    }
    float* Yb = Y + (size_t)b * CH * NSP;
#pragma unroll
    for (int i = 0; i < 4; i++)
#pragma unroll
        for (int j = 0; j < 4; j++) {
            int c = c0 + ty + 16 * i, n = n0 + tx + 16 * j;
            Yb[(size_t)c * NSP + n] = acc[i][j] + Xb[(size_t)c * NSP + n];
        }
}

// K4: S[n][m] = sum_c y[c][n] * y[c][m]   (Gram over spatial, K = 512)
__global__ __launch_bounds__(256) void k4_gram(const float* __restrict__ Yb,
                                               float* __restrict__ S) {
    __shared__ float As[TS][KT + 1];  // [n-row][k]
    __shared__ float Bs[KT][TS + 1];  // [k][m-col]
    const int r0 = blockIdx.y * TS, c0 = blockIdx.x * TS;
    const int tid = threadIdx.x;
    const int tx = tid & 15, ty = tid >> 4;
    const int lane = tid & 63, lrow = tid >> 6;
    float acc[4][4] = {};
    for (int k0 = 0; k0 < CH; k0 += KT) {
#pragma unroll
        for (int r = 0; r < 16; r++) {
            int kk = lrow + 4 * r;
            As[lane][kk] = Yb[(size_t)(k0 + kk) * NSP + r0 + lane]; // transposed store, stride 65
            Bs[kk][lane] = Yb[(size_t)(k0 + kk) * NSP + c0 + lane];
        }
        __syncthreads();
#pragma unroll
        for (int k = 0; k < KT; k++) {
            float a[4], bv[4];
#pragma unroll
            for (int i = 0; i < 4; i++) a[i] = As[ty + 16 * i][k];
#pragma unroll
            for (int j = 0; j < 4; j++) bv[j] = Bs[k][tx + 16 * j];
#pragma unroll
            for (int i = 0; i < 4; i++)
#pragma unroll
                for (int j = 0; j < 4; j++) acc[i][j] += a[i] * bv[j];
        }
        __syncthreads();
    }
#pragma unroll
    for (int i = 0; i < 4; i++)
#pragma unroll
        for (int j = 0; j < 4; j++)
            S[(size_t)(r0 + ty + 16 * i) * NSP + c0 + tx + 16 * j] = acc[i][j];
}

// K6: out[c][m] = sum_n y[c][n] * P[m][n] + y[c][m]   (P rows softmaxed)
__global__ __launch_bounds__(256) void k6_out2(const float* __restrict__ Yb,
                                               const float* __restrict__ P,
                                               float* __restrict__ Ob) {
    __shared__ float As[TS][KT + 1];  // [c-row][k=n]
    __shared__ float Bs[KT][TS + 1];  // [k=n][m-col]
    const int c0 = blockIdx.y * TS, m0 = blockIdx.x * TS;
    const int tid = threadIdx.x;
    const int tx = tid & 15, ty = tid >> 4;
    const int lane = tid & 63, lrow = tid >> 6;
    float acc[4][4] = {};
    for (int k0 = 0; k0 < NSP; k0 += KT) {
#pragma unroll
        for (int r = 0; r < 16; r++) {
            int rr = lrow + 4 * r;
            As[rr][lane] = Yb[(size_t)(c0 + rr) * NSP + k0 + lane];  // A(c,n) contiguous n
            Bs[lane][rr] = P[(size_t)(m0 + rr) * NSP + k0 + lane];   // P row m contiguous n, transposed store
        }
        __syncthreads();
#pragma unroll
        for (int k = 0; k < KT; k++) {
            float a[4], bv[4];
#pragma unroll
            for (int i = 0; i < 4; i++) a[i] = As[ty + 16 * i][k];
#pragma unroll
            for (int j = 0; j < 4; j++) bv[j] = Bs[k][tx + 16 * j];
#pragma unroll
            for (int i = 0; i < 4; i++)
#pragma unroll
                for (int j = 0; j < 4; j++) acc[i][j] += a[i] * bv[j];
        }
        __syncthreads();
    }
#pragma unroll
    for (int i = 0; i < 4; i++)
#pragma unroll
        for (int j = 0; j < 4; j++) {
            int c = c0 + ty + 16 * i, mm = m0 + tx + 16 * j;
            Ob[(size_t)c * NSP + mm] = acc[i][j] + Yb[(size_t)c * NSP + mm];
        }
}

extern "C" void kernel_launch(void* const* d_in, const int* in_sizes, int n_in,
                              void* d_out, int out_size, void* d_ws, size_t ws_size,
                              hipStream_t stream) {
    const float* x = (const float*)d_in[0];
    float* out = (float*)d_out;
    float* ws = (float*)d_ws;

    // workspace layout (floats): Y [B*C*N] | L [B*C*C] | S [N*N] (reused per batch)
    float* Y = ws;
    float* Lg = Y + (size_t)BATCH * CH * NSP;
    float* S = Lg + (size_t)BATCH * CH * CH;

    // Stage 1: channel attention (all batches concurrently)
    k1_logits<<<dim3(CH / TS, CH / TS, BATCH), 256, 0, stream>>>(x, Lg);
    softmax_rows<<<dim3(BATCH * CH), 256, 0, stream>>>(Lg, CH);
    k3_out1<<<dim3(NSP / TS, CH / TS, BATCH), 256, 0, stream>>>(Lg, x, Y);

    // Stage 2: positional attention, batches sequential (share one S buffer)
    for (int b = 0; b < BATCH; b++) {
        const float* Yb = Y + (size_t)b * CH * NSP;
        k4_gram<<<dim3(NSP / TS, NSP / TS), 256, 0, stream>>>(Yb, S);
        softmax_rows<<<dim3(NSP), 256, 0, stream>>>(S, NSP);
        k6_out2<<<dim3(NSP / TS, CH / TS), 256, 0, stream>>>(Yb, S, out + (size_t)b * CH * NSP);
    }
}

// Round 2
// 978.674 us; speedup vs baseline: 2.9479x; 2.9479x over previous
//
#include <hip/hip_runtime.h>

#define BATCH 4
#define CH 512
#define NSP 4096   // 64*64 spatial
#define TS 64
#define KT 64

typedef __attribute__((ext_vector_type(8))) short bfrag8;  // 8 bf16 (4 VGPRs)
typedef __attribute__((ext_vector_type(4))) float f32x4;

#define AS1 __attribute__((address_space(1)))
#define AS3 __attribute__((address_space(3)))
__device__ __forceinline__ void gload16(const void* g, void* l) {
    __builtin_amdgcn_global_load_lds((const AS1 void*)g, (AS3 void*)l, 16, 0, 0);
}

// ---------------------------------------------------------------------------
// Stage 1 (fp32, known-correct from R1): k1 logits, softmax, k3 -> Y
// ---------------------------------------------------------------------------

__global__ __launch_bounds__(256) void k1_logits(const float* __restrict__ X,
                                                 float* __restrict__ Lg) {
    __shared__ float As[TS][KT + 1];
    __shared__ float Bs[KT][TS + 1];
    const int b = blockIdx.z;
    const float* base = X + (size_t)b * CH * NSP;
    const int c0 = blockIdx.y * TS, d0 = blockIdx.x * TS;
    const int tid = threadIdx.x;
    const int tx = tid & 15, ty = tid >> 4;
    const int lane = tid & 63, lrow = tid >> 6;
    float acc[4][4] = {};
    for (int k0 = 0; k0 < NSP; k0 += KT) {
#pragma unroll
        for (int r = 0; r < 16; r++) {
            int row = lrow + 4 * r;
            As[row][lane] = base[(size_t)(c0 + row) * NSP + k0 + lane];
            Bs[row][lane] = base[(size_t)(k0 + row) * CH + d0 + lane];
        }
        __syncthreads();
#pragma unroll
        for (int k = 0; k < KT; k++) {
            float a[4], bv[4];
#pragma unroll
            for (int i = 0; i < 4; i++) a[i] = As[ty + 16 * i][k];
#pragma unroll
            for (int j = 0; j < 4; j++) bv[j] = Bs[k][tx + 16 * j];
#pragma unroll
            for (int i = 0; i < 4; i++)
#pragma unroll
                for (int j = 0; j < 4; j++) acc[i][j] += a[i] * bv[j];
        }
        __syncthreads();
    }
    float* Lb = Lg + (size_t)b * CH * CH;
#pragma unroll
    for (int i = 0; i < 4; i++)
#pragma unroll
        for (int j = 0; j < 4; j++)
            Lb[(size_t)(c0 + ty + 16 * i) * CH + d0 + tx + 16 * j] = acc[i][j];
}

__global__ __launch_bounds__(256) void softmax_rows(float* __restrict__ data, int len) {
    __shared__ float buf[4096];
    __shared__ float red[256];
    const int tid = threadIdx.x;
    float* row = data + (size_t)blockIdx.x * len;
    float m = -INFINITY;
    for (int i = tid; i < len; i += 256) {
        float v = row[i];
        buf[i] = v;
        m = fmaxf(m, v);
    }
    red[tid] = m;
    __syncthreads();
    for (int s = 128; s > 0; s >>= 1) {
        if (tid < s) red[tid] = fmaxf(red[tid], red[tid + s]);
        __syncthreads();
    }
    m = red[0];
    __syncthreads();
    float sum = 0.f;
    for (int i = tid; i < len; i += 256) {
        float e = expf(buf[i] - m);
        buf[i] = e;
        sum += e;
    }
    red[tid] = sum;
    __syncthreads();
    for (int s = 128; s > 0; s >>= 1) {
        if (tid < s) red[tid] += red[tid + s];
        __syncthreads();
    }
    float inv = 1.0f / red[0];
    for (int i = tid; i < len; i += 256) row[i] = buf[i] * inv;
}

__global__ __launch_bounds__(256) void k3_out1(const float* __restrict__ Att,
                                               const float* __restrict__ X,
                                               float* __restrict__ Y) {
    __shared__ float As[TS][KT + 1];
    __shared__ float Bs[KT][TS + 1];
    const int b = blockIdx.z;
    const float* Ab = Att + (size_t)b * CH * CH;
    const float* Xb = X + (size_t)b * CH * NSP;
    const int c0 = blockIdx.y * TS, n0 = blockIdx.x * TS;
    const int tid = threadIdx.x;
    const int tx = tid & 15, ty = tid >> 4;
    const int lane = tid & 63, lrow = tid >> 6;
    float acc[4][4] = {};
    for (int k0 = 0; k0 < CH; k0 += KT) {
#pragma unroll
        for (int r = 0; r < 16; r++) {
            int row = lrow + 4 * r;
            As[row][lane] = Ab[(size_t)(c0 + row) * CH + k0 + lane];
            Bs[row][lane] = Xb[(size_t)(k0 + row) * NSP + n0 + lane];
        }
        __syncthreads();
#pragma unroll
        for (int k = 0; k < KT; k++) {
            float a[4], bv[4];
#pragma unroll
            for (int i = 0; i < 4; i++) a[i] = As[ty + 16 * i][k];
#pragma unroll
            for (int j = 0; j < 4; j++) bv[j] = Bs[k][tx + 16 * j];
#pragma unroll
            for (int i = 0; i < 4; i++)
#pragma unroll
                for (int j = 0; j < 4; j++) acc[i][j] += a[i] * bv[j];
        }
        __syncthreads();
    }
    float* Yb = Y + (size_t)b * CH * NSP;
#pragma unroll
    for (int i = 0; i < 4; i++)
#pragma unroll
        for (int j = 0; j < 4; j++) {
            int c = c0 + ty + 16 * i, n = n0 + tx + 16 * j;
            Yb[(size_t)c * NSP + n] = acc[i][j] + Xb[(size_t)c * NSP + n];
        }
}

// ---------------------------------------------------------------------------
// Split-bf16 helpers: y = hi + lo, hi = trunc16(y), lo = trunc16(y - hi).
// Residual after hi+lo <= 2^-16 relative.
// ---------------------------------------------------------------------------
__device__ __forceinline__ void split_bf16(float y, unsigned short& h, unsigned short& l) {
    unsigned int u = __float_as_uint(y);
    h = (unsigned short)(u >> 16);
    float r = y - __uint_as_float(((unsigned int)h) << 16);
    l = (unsigned short)(__float_as_uint(r) >> 16);
}
__device__ __forceinline__ float join_bf16(unsigned short h, unsigned short l) {
    return __uint_as_float(((unsigned int)h) << 16) + __uint_as_float(((unsigned int)l) << 16);
}

// Y fp32 [B][C][N] -> Yhi, Ylo bf16-bits [B][C][N]
__global__ __launch_bounds__(256) void k_convert(const float* __restrict__ Y,
                                                 unsigned short* __restrict__ Yhi,
                                                 unsigned short* __restrict__ Ylo) {
    size_t i = ((size_t)blockIdx.x * 256 + threadIdx.x) * 4;
    float4 v = *(const float4*)(Y + i);
    ushort4 h, l;
    split_bf16(v.x, h.x, l.x);
    split_bf16(v.y, h.y, l.y);
    split_bf16(v.z, h.z, l.z);
    split_bf16(v.w, h.w, l.w);
    *(ushort4*)(Yhi + i) = h;
    *(ushort4*)(Ylo + i) = l;
}

// Y fp32 [B][C][N] -> YThi, YTlo bf16-bits [B][N][C] (transposed)
__global__ __launch_bounds__(256) void k_transpose(const float* __restrict__ Y,
                                                   unsigned short* __restrict__ YThi,
                                                   unsigned short* __restrict__ YTlo) {
    __shared__ unsigned int t[64][65];
    const int b = blockIdx.z;
    const int n0 = blockIdx.x * 64, c0 = blockIdx.y * 64;
    const int tid = threadIdx.x;
    const float* Yb = Y + (size_t)b * CH * NSP;
    const int r = tid >> 4;          // 0..15
    const int col4 = (tid & 15) * 4; // 0..60
#pragma unroll
    for (int it = 0; it < 4; it++) {
        int cl = r + it * 16;
        float4 v = *(const float4*)(Yb + (size_t)(c0 + cl) * NSP + n0 + col4);
        unsigned short h, l;
        split_bf16(v.x, h, l); t[cl][col4 + 0] = ((unsigned int)h << 16) | l;
        split_bf16(v.y, h, l); t[cl][col4 + 1] = ((unsigned int)h << 16) | l;
        split_bf16(v.z, h, l); t[cl][col4 + 2] = ((unsigned int)h << 16) | l;
        split_bf16(v.w, h, l); t[cl][col4 + 3] = ((unsigned int)h << 16) | l;
    }
    __syncthreads();
    unsigned short* Hb = YThi + (size_t)b * NSP * CH;
    unsigned short* Lb = YTlo + (size_t)b * NSP * CH;
#pragma unroll
    for (int it = 0; it < 4; it++) {
        int nl = r + it * 16;
        unsigned int p0 = t[col4 + 0][nl];
        unsigned int p1 = t[col4 + 1][nl];
        unsigned int p2 = t[col4 + 2][nl];
        unsigned int p3 = t[col4 + 3][nl];
        ushort4 hv, lv;
        hv.x = p0 >> 16; hv.y = p1 >> 16; hv.z = p2 >> 16; hv.w = p3 >> 16;
        lv.x = p0 & 0xffff; lv.y = p1 & 0xffff; lv.z = p2 & 0xffff; lv.w = p3 & 0xffff;
        *(ushort4*)(Hb + (size_t)(n0 + nl) * CH + c0 + col4) = hv;
        *(ushort4*)(Lb + (size_t)(n0 + nl) * CH + c0 + col4) = lv;
    }
}

// ---------------------------------------------------------------------------
// k4 MFMA: S[n][m] = sum_c y[c][n] y[c][m], 3-term split-bf16.
// A and B tiles both come from YT [N][C]. Tile 128x128, BK=32, 4 waves,
// each wave a 64x64 quadrant (4x4 mfma tiles of 16x16x32).
// ---------------------------------------------------------------------------
__global__ __launch_bounds__(256, 2) void k4_mfma(const unsigned short* __restrict__ YThi,
                                                  const unsigned short* __restrict__ YTlo,
                                                  float* __restrict__ S) {
    __shared__ __align__(16) char smem[32768];
    char* Ahi = smem;
    char* Alo = smem + 8192;
    char* Bhi = smem + 16384;
    char* Blo = smem + 24576;
    const int tid = threadIdx.x, lane = tid & 63, w = tid >> 6;
    const int wr = w >> 1, wc = w & 1;
    const int n0 = blockIdx.y * 128, m0 = blockIdx.x * 128;
    const int rl = lane >> 2;        // sub-row within 16-row group
    const int cb = (lane & 3) * 8;   // ushort offset of this lane's 16B
    f32x4 acc[4][4];
#pragma unroll
    for (int i = 0; i < 4; i++)
#pragma unroll
        for (int j = 0; j < 4; j++) acc[i][j] = (f32x4){0.f, 0.f, 0.f, 0.f};

    for (int k0 = 0; k0 < CH; k0 += 32) {
#pragma unroll
        for (int s = 0; s < 2; s++) {
            int idx = w * 2 + s;
            int row = 16 * idx + rl;
            gload16(YThi + (size_t)(n0 + row) * CH + k0 + cb, Ahi + idx * 1024);
            gload16(YTlo + (size_t)(n0 + row) * CH + k0 + cb, Alo + idx * 1024);
            gload16(YThi + (size_t)(m0 + row) * CH + k0 + cb, Bhi + idx * 1024);
            gload16(YTlo + (size_t)(m0 + row) * CH + k0 + cb, Blo + idx * 1024);
        }
        __syncthreads();
        bfrag8 ah[4], al[4], bh[4], bl[4];
        const int q16 = (lane >> 4) * 16;
        const int l15 = (lane & 15);
#pragma unroll
        for (int i = 0; i < 4; i++) {
            int offa = (wr * 64 + i * 16 + l15) * 64 + q16;
            ah[i] = *(const bfrag8*)(Ahi + offa);
            al[i] = *(const bfrag8*)(Alo + offa);
            int offb = (wc * 64 + i * 16 + l15) * 64 + q16;
            bh[i] = *(const bfrag8*)(Bhi + offb);
            bl[i] = *(const bfrag8*)(Blo + offb);
        }
#pragma unroll
        for (int i = 0; i < 4; i++)
#pragma unroll
            for (int j = 0; j < 4; j++) {
                acc[i][j] = __builtin_amdgcn_mfma_f32_16x16x32_bf16(ah[i], bh[j], acc[i][j], 0, 0, 0);
                acc[i][j] = __builtin_amdgcn_mfma_f32_16x16x32_bf16(ah[i], bl[j], acc[i][j], 0, 0, 0);
                acc[i][j] = __builtin_amdgcn_mfma_f32_16x16x32_bf16(al[i], bh[j], acc[i][j], 0, 0, 0);
            }
        __syncthreads();
    }
    const int col = lane & 15, qr = (lane >> 4) * 4;
#pragma unroll
    for (int i = 0; i < 4; i++)
#pragma unroll
        for (int j = 0; j < 4; j++)
#pragma unroll
            for (int r = 0; r < 4; r++)
                S[(size_t)(n0 + wr * 64 + 16 * i + qr + r) * NSP + m0 + wc * 64 + 16 * j + col] =
                    acc[i][j][r];
}

// Row softmax of S (4096 rows), writing P packed hi/lo in place:
// row m bytes [0,8KB) = 4096 bf16 hi, [8KB,16KB) = 4096 bf16 lo.
__global__ __launch_bounds__(256) void k_softmax_pack(float* __restrict__ S) {
    __shared__ float buf[4096];
    __shared__ float red[256];
    const int tid = threadIdx.x;
    float* row = S + (size_t)blockIdx.x * NSP;
    float m = -INFINITY;
#pragma unroll
    for (int it = 0; it < 4; it++) {
        int i = (tid + it * 256) * 4;
        float4 v = *(const float4*)(row + i);
        buf[i] = v.x; buf[i + 1] = v.y; buf[i + 2] = v.z; buf[i + 3] = v.w;
        m = fmaxf(m, fmaxf(fmaxf(v.x, v.y), fmaxf(v.z, v.w)));
    }
    red[tid] = m;
    __syncthreads();
    for (int s = 128; s > 0; s >>= 1) {
        if (tid < s) red[tid] = fmaxf(red[tid], red[tid + s]);
        __syncthreads();
    }
    m = red[0];
    __syncthreads();
    float sum = 0.f;
#pragma unroll
    for (int it = 0; it < 4; it++) {
        int i = (tid + it * 256) * 4;
        float e0 = expf(buf[i] - m), e1 = expf(buf[i + 1] - m);
        float e2 = expf(buf[i + 2] - m), e3 = expf(buf[i + 3] - m);
        buf[i] = e0; buf[i + 1] = e1; buf[i + 2] = e2; buf[i + 3] = e3;
        sum += e0 + e1 + e2 + e3;
    }
    red[tid] = sum;
    __syncthreads();
    for (int s = 128; s > 0; s >>= 1) {
        if (tid < s) red[tid] += red[tid + s];
        __syncthreads();
    }
    float inv = 1.0f / red[0];
    unsigned short* u = (unsigned short*)row;
#pragma unroll
    for (int it = 0; it < 4; it++) {
        int i = (tid + it * 256) * 4;
        ushort4 hv, lv;
        split_bf16(buf[i] * inv, hv.x, lv.x);
        split_bf16(buf[i + 1] * inv, hv.y, lv.y);
        split_bf16(buf[i + 2] * inv, hv.z, lv.z);
        split_bf16(buf[i + 3] * inv, hv.w, lv.w);
        *(ushort4*)(u + i) = hv;
        *(ushort4*)(u + NSP + i) = lv;
    }
}

// k6 MFMA: out[c][m] = sum_n y[c][n] P[m][n] (+ residual later).
// A from Yhi/Ylo [C][N]; B from packed P rows. Split-K=4 -> partials Pp[z].
__global__ __launch_bounds__(256, 2) void k6_mfma(const unsigned short* __restrict__ Yhi,
                                                  const unsigned short* __restrict__ Ylo,
                                                  const unsigned short* __restrict__ Ppk,
                                                  float* __restrict__ Pp) {
    __shared__ __align__(16) char smem[32768];
    char* Ahi = smem;
    char* Alo = smem + 8192;
    char* Bhi = smem + 16384;
    char* Blo = smem + 24576;
    const int tid = threadIdx.x, lane = tid & 63, w = tid >> 6;
    const int wr = w >> 1, wc = w & 1;
    const int m0 = blockIdx.x * 128, c0 = blockIdx.y * 128, z = blockIdx.z;
    const int kb = z * 1024;
    const int rl = lane >> 2;
    const int cb = (lane & 3) * 8;
    f32x4 acc[4][4];
#pragma unroll
    for (int i = 0; i < 4; i++)
#pragma unroll
        for (int j = 0; j < 4; j++) acc[i][j] = (f32x4){0.f, 0.f, 0.f, 0.f};

    for (int k0 = 0; k0 < 1024; k0 += 32) {
        const int kk = kb + k0;
#pragma unroll
        for (int s = 0; s < 2; s++) {
            int idx = w * 2 + s;
            int row = 16 * idx + rl;
            gload16(Yhi + (size_t)(c0 + row) * NSP + kk + cb, Ahi + idx * 1024);
            gload16(Ylo + (size_t)(c0 + row) * NSP + kk + cb, Alo + idx * 1024);
            const unsigned short* pr = Ppk + (size_t)(m0 + row) * 8192;
            gload16(pr + kk + cb, Bhi + idx * 1024);
            gload16(pr + 4096 + kk + cb, Blo + idx * 1024);
        }
        __syncthreads();
        bfrag8 ah[4], al[4], bh[4], bl[4];
        const int q16 = (lane >> 4) * 16;
        const int l15 = (lane & 15);
#pragma unroll
        for (int i = 0; i < 4; i++) {
            int offa = (wr * 64 + i * 16 + l15) * 64 + q16;
            ah[i] = *(const bfrag8*)(Ahi + offa);
            al[i] = *(const bfrag8*)(Alo + offa);
            int offb = (wc * 64 + i * 16 + l15) * 64 + q16;
            bh[i] = *(const bfrag8*)(Bhi + offb);
            bl[i] = *(const bfrag8*)(Blo + offb);
        }
#pragma unroll
        for (int i = 0; i < 4; i++)
#pragma unroll
            for (int j = 0; j < 4; j++) {
                acc[i][j] = __builtin_amdgcn_mfma_f32_16x16x32_bf16(ah[i], bh[j], acc[i][j], 0, 0, 0);
                acc[i][j] = __builtin_amdgcn_mfma_f32_16x16x32_bf16(ah[i], bl[j], acc[i][j], 0, 0, 0);
                acc[i][j] = __builtin_amdgcn_mfma_f32_16x16x32_bf16(al[i], bh[j], acc[i][j], 0, 0, 0);
            }
        __syncthreads();
    }
    float* out = Pp + (size_t)z * CH * NSP;
    const int col = lane & 15, qr = (lane >> 4) * 4;
#pragma unroll
    for (int i = 0; i < 4; i++)
#pragma unroll
        for (int j = 0; j < 4; j++)
#pragma unroll
            for (int r = 0; r < 4; r++)
                out[(size_t)(c0 + wr * 64 + 16 * i + qr + r) * NSP + m0 + wc * 64 + 16 * j + col] =
                    acc[i][j][r];
}

// out = Pp[0]+Pp[1]+Pp[2]+Pp[3] + (Yhi+Ylo)  (residual reconstructed from split)
__global__ __launch_bounds__(256) void k_combine(const float* __restrict__ Pp,
                                                 const unsigned short* __restrict__ Yhi,
                                                 const unsigned short* __restrict__ Ylo,
                                                 float* __restrict__ outb) {
    const size_t CN = (size_t)CH * NSP;
    size_t i = ((size_t)blockIdx.x * 256 + threadIdx.x) * 4;
    float4 a = *(const float4*)(Pp + i);
    float4 b = *(const float4*)(Pp + CN + i);
    float4 c = *(const float4*)(Pp + 2 * CN + i);
    float4 d = *(const float4*)(Pp + 3 * CN + i);
    ushort4 h = *(const ushort4*)(Yhi + i);
    ushort4 l = *(const ushort4*)(Ylo + i);
    float4 o;
    o.x = a.x + b.x + c.x + d.x + join_bf16(h.x, l.x);
    o.y = a.y + b.y + c.y + d.y + join_bf16(h.y, l.y);
    o.z = a.z + b.z + c.z + d.z + join_bf16(h.z, l.z);
    o.w = a.w + b.w + c.w + d.w + join_bf16(h.w, l.w);
    *(float4*)(outb + i) = o;
}

extern "C" void kernel_launch(void* const* d_in, const int* in_sizes, int n_in,
                              void* d_out, int out_size, void* d_ws, size_t ws_size,
                              hipStream_t stream) {
    const float* x = (const float*)d_in[0];
    float* out = (float*)d_out;

    // workspace layout (bytes)
    char* p = (char*)d_ws;
    float* Y = (float*)p;               p += (size_t)BATCH * CH * NSP * 4;   // 32 MB
    float* Lg = (float*)p;              p += (size_t)BATCH * CH * CH * 4;    // 4 MB
    unsigned short* Yhi = (unsigned short*)p;  p += (size_t)BATCH * CH * NSP * 2;  // 16 MB
    unsigned short* Ylo = (unsigned short*)p;  p += (size_t)BATCH * CH * NSP * 2;
    unsigned short* YThi = (unsigned short*)p; p += (size_t)BATCH * NSP * CH * 2;
    unsigned short* YTlo = (unsigned short*)p; p += (size_t)BATCH * NSP * CH * 2;
    float* S = (float*)p;               p += (size_t)NSP * NSP * 4;          // 64 MB
    float* Pp = (float*)p;              p += (size_t)4 * CH * NSP * 4;       // 32 MB

    // Stage 1: channel attention (fp32)
    k1_logits<<<dim3(CH / TS, CH / TS, BATCH), 256, 0, stream>>>(x, Lg);
    softmax_rows<<<dim3(BATCH * CH), 256, 0, stream>>>(Lg, CH);
    k3_out1<<<dim3(NSP / TS, CH / TS, BATCH), 256, 0, stream>>>(Lg, x, Y);

    // Split Y into bf16 hi/lo, row-major and transposed
    k_convert<<<dim3((BATCH * CH * NSP) / (4 * 256)), 256, 0, stream>>>(Y, Yhi, Ylo);
    k_transpose<<<dim3(NSP / 64, CH / 64, BATCH), 256, 0, stream>>>(Y, YThi, YTlo);

    // Stage 2: positional attention per batch (MFMA)
    for (int b = 0; b < BATCH; b++) {
        const unsigned short* YThib = YThi + (size_t)b * NSP * CH;
        const unsigned short* YTlob = YTlo + (size_t)b * NSP * CH;
        const unsigned short* Yhib = Yhi + (size_t)b * CH * NSP;
        const unsigned short* Ylob = Ylo + (size_t)b * CH * NSP;
        k4_mfma<<<dim3(NSP / 128, NSP / 128), 256, 0, stream>>>(YThib, YTlob, S);
        k_softmax_pack<<<dim3(NSP), 256, 0, stream>>>(S);
        k6_mfma<<<dim3(NSP / 128, CH / 128, 4), 256, 0, stream>>>(Yhib, Ylob,
                                                                  (const unsigned short*)S, Pp);
        k_combine<<<dim3((CH * NSP) / (4 * 256)), 256, 0, stream>>>(Pp, Yhib, Ylob,
                                                                    out + (size_t)b * CH * NSP);
    }
}

// Round 4
// 827.925 us; speedup vs baseline: 3.4846x; 1.1821x over previous
//
#include <hip/hip_runtime.h>

#define BATCH 4
#define CH 512
#define NSP 4096   // 64*64 spatial

typedef __attribute__((ext_vector_type(8))) short bfrag8;  // 8 bf16 (4 VGPRs)
typedef __attribute__((ext_vector_type(4))) float f32x4;
typedef unsigned short u16;

#define AS1 __attribute__((address_space(1)))
#define AS3 __attribute__((address_space(3)))
__device__ __forceinline__ void gload16(const void* g, void* l) {
    __builtin_amdgcn_global_load_lds((const AS1 void*)g, (AS3 void*)l, 16, 0, 0);
}

// ---------------------------------------------------------------------------
// split-bf16: y = hi + lo exactly to ~2^-17 relative; fp32 accumulate in MFMA
// ---------------------------------------------------------------------------
__device__ __forceinline__ void split_bf16(float y, u16& h, u16& l) {
    unsigned int u = __float_as_uint(y);
    h = (u16)(u >> 16);
    float r = y - __uint_as_float(((unsigned int)h) << 16);
    l = (u16)(__float_as_uint(r) >> 16);
}
__device__ __forceinline__ float join_bf16(u16 h, u16 l) {
    return __uint_as_float(((unsigned int)h) << 16) + __uint_as_float(((unsigned int)l) << 16);
}

// elementwise: fp32 -> hi/lo bf16 bits (flat; serves [C][N] and [N][C] views)
__global__ __launch_bounds__(256) void k_convert(const float* __restrict__ Y,
                                                 u16* __restrict__ Yhi,
                                                 u16* __restrict__ Ylo) {
    size_t i = ((size_t)blockIdx.x * 256 + threadIdx.x) * 4;
    float4 v = *(const float4*)(Y + i);
    ushort4 h, l;
    split_bf16(v.x, h.x, l.x);
    split_bf16(v.y, h.y, l.y);
    split_bf16(v.z, h.z, l.z);
    split_bf16(v.w, h.w, l.w);
    *(ushort4*)(Yhi + i) = h;
    *(ushort4*)(Ylo + i) = l;
}

// transpose a split pair: src [R][Cc] -> dst [Cc][R] (per-batch stride R*Cc)
__global__ __launch_bounds__(256) void k_transpose_split(const u16* __restrict__ Hs,
                                                         const u16* __restrict__ Ls,
                                                         u16* __restrict__ Hd,
                                                         u16* __restrict__ Ld,
                                                         int R, int Cc) {
    __shared__ unsigned int t[64][65];
    const size_t off = (size_t)blockIdx.z * R * Cc;
    const int r0 = blockIdx.x * 64, c0 = blockIdx.y * 64;
    const int r = threadIdx.x >> 4, col4 = (threadIdx.x & 15) * 4;
#pragma unroll
    for (int it = 0; it < 4; it++) {
        int rl = r + it * 16;
        ushort4 h = *(const ushort4*)(Hs + off + (size_t)(r0 + rl) * Cc + c0 + col4);
        ushort4 l = *(const ushort4*)(Ls + off + (size_t)(r0 + rl) * Cc + c0 + col4);
        t[rl][col4 + 0] = ((unsigned int)h.x << 16) | l.x;
        t[rl][col4 + 1] = ((unsigned int)h.y << 16) | l.y;
        t[rl][col4 + 2] = ((unsigned int)h.z << 16) | l.z;
        t[rl][col4 + 3] = ((unsigned int)h.w << 16) | l.w;
    }
    __syncthreads();
#pragma unroll
    for (int it = 0; it < 4; it++) {
        int cl = r + it * 16;
        unsigned int p0 = t[col4 + 0][cl];
        unsigned int p1 = t[col4 + 1][cl];
        unsigned int p2 = t[col4 + 2][cl];
        unsigned int p3 = t[col4 + 3][cl];
        ushort4 hv, lv;
        hv.x = p0 >> 16; hv.y = p1 >> 16; hv.z = p2 >> 16; hv.w = p3 >> 16;
        lv.x = p0 & 0xffff; lv.y = p1 & 0xffff; lv.z = p2 & 0xffff; lv.w = p3 & 0xffff;
        *(ushort4*)(Hd + off + (size_t)(c0 + cl) * R + r0 + col4) = hv;
        *(ushort4*)(Ld + off + (size_t)(c0 + cl) * R + r0 + col4) = lv;
    }
}

// ---------------------------------------------------------------------------
// k1 MFMA: L[c][d] = sum_n x[c][n] * pk[n][d], 3-term split. Tile 128x128, BK=32.
// A = XHi/XLo viewed [C][N] (k=n contiguous); B = XT2 [d][n] = pk^T (k=n contiguous).
// ---------------------------------------------------------------------------
__global__ __launch_bounds__(256, 2) void k1_mfma(const u16* __restrict__ XHi,
                                                  const u16* __restrict__ XLo,
                                                  const u16* __restrict__ XT2hi,
                                                  const u16* __restrict__ XT2lo,
                                                  float* __restrict__ Lg) {
    __shared__ __align__(16) char smem[32768];
    char* Ahi = smem;
    char* Alo = smem + 8192;
    char* Bhi = smem + 16384;
    char* Blo = smem + 24576;
    const int b = blockIdx.z;
    const size_t boff = (size_t)b * CH * NSP;
    const int tid = threadIdx.x, lane = tid & 63, w = tid >> 6;
    const int wr = w >> 1, wc = w & 1;
    const int c0 = blockIdx.y * 128, d0 = blockIdx.x * 128;
    const int rl = lane >> 2;
    const int cb = (lane & 3) * 8;
    f32x4 acc[4][4];
#pragma unroll
    for (int i = 0; i < 4; i++)
#pragma unroll
        for (int j = 0; j < 4; j++) acc[i][j] = (f32x4){0.f, 0.f, 0.f, 0.f};

    for (int k0 = 0; k0 < NSP; k0 += 32) {
#pragma unroll
        for (int s = 0; s < 2; s++) {
            int idx = w * 2 + s;
            int row = 16 * idx + rl;
            gload16(XHi + boff + (size_t)(c0 + row) * NSP + k0 + cb, Ahi + idx * 1024);
            gload16(XLo + boff + (size_t)(c0 + row) * NSP + k0 + cb, Alo + idx * 1024);
            gload16(XT2hi + boff + (size_t)(d0 + row) * NSP + k0 + cb, Bhi + idx * 1024);
            gload16(XT2lo + boff + (size_t)(d0 + row) * NSP + k0 + cb, Blo + idx * 1024);
        }
        __syncthreads();
        bfrag8 ah[4], al[4], bh[4], bl[4];
        const int q16 = (lane >> 4) * 16;
        const int l15 = (lane & 15);
#pragma unroll
        for (int i = 0; i < 4; i++) {
            int offa = (wr * 64 + i * 16 + l15) * 64 + q16;
            ah[i] = *(const bfrag8*)(Ahi + offa);
            al[i] = *(const bfrag8*)(Alo + offa);
            int offb = (wc * 64 + i * 16 + l15) * 64 + q16;
            bh[i] = *(const bfrag8*)(Bhi + offb);
            bl[i] = *(const bfrag8*)(Blo + offb);
        }
#pragma unroll
        for (int i = 0; i < 4; i++)
#pragma unroll
            for (int j = 0; j < 4; j++) {
                acc[i][j] = __builtin_amdgcn_mfma_f32_16x16x32_bf16(ah[i], bh[j], acc[i][j], 0, 0, 0);
                acc[i][j] = __builtin_amdgcn_mfma_f32_16x16x32_bf16(ah[i], bl[j], acc[i][j], 0, 0, 0);
                acc[i][j] = __builtin_amdgcn_mfma_f32_16x16x32_bf16(al[i], bh[j], acc[i][j], 0, 0, 0);
            }
        __syncthreads();
    }
    float* Lb = Lg + (size_t)b * CH * CH;
    const int col = lane & 15, qr = (lane >> 4) * 4;
#pragma unroll
    for (int i = 0; i < 4; i++)
#pragma unroll
        for (int j = 0; j < 4; j++)
#pragma unroll
            for (int r = 0; r < 4; r++)
                Lb[(size_t)(c0 + wr * 64 + 16 * i + qr + r) * CH + d0 + wc * 64 + 16 * j + col] =
                    acc[i][j][r];
}

// softmax over rows of length 512, writing packed hi/lo bf16 in place:
// row c (512 floats = 1024 u16): [0,512) hi, [512,1024) lo
__global__ __launch_bounds__(256) void k_softmax_pack512(float* __restrict__ Lg) {
    __shared__ float buf[512];
    __shared__ float red[256];
    const int tid = threadIdx.x;
    float* row = Lg + (size_t)blockIdx.x * 512;
    float2 v = *(const float2*)(row + tid * 2);
    buf[tid * 2] = v.x;
    buf[tid * 2 + 1] = v.y;
    red[tid] = fmaxf(v.x, v.y);
    __syncthreads();
    for (int s = 128; s > 0; s >>= 1) {
        if (tid < s) red[tid] = fmaxf(red[tid], red[tid + s]);
        __syncthreads();
    }
    float m = red[0];
    __syncthreads();
    float e0 = expf(buf[tid * 2] - m), e1 = expf(buf[tid * 2 + 1] - m);
    buf[tid * 2] = e0;
    buf[tid * 2 + 1] = e1;
    red[tid] = e0 + e1;
    __syncthreads();
    for (int s = 128; s > 0; s >>= 1) {
        if (tid < s) red[tid] += red[tid + s];
        __syncthreads();
    }
    float inv = 1.0f / red[0];
    u16* u = (u16*)row;
    u16 h0, l0, h1, l1;
    split_bf16(buf[tid * 2] * inv, h0, l0);
    split_bf16(buf[tid * 2 + 1] * inv, h1, l1);
    __syncthreads();  // all reads of row done before overwrite
    u[tid * 2] = h0;
    u[tid * 2 + 1] = h1;
    u[512 + tid * 2] = l0;
    u[512 + tid * 2 + 1] = l1;
}

// ---------------------------------------------------------------------------
// k3 MFMA: Y[c][n] = sum_d A[c][d] * pq[d][n] + x[c][n]; writes Yhi/Ylo split.
// A = packed softmax rows (len 512, k=d contiguous);
// B = XT1 [n][c] = pq^T  (XT1[n][d] = xflat[d*N+n], k=d contiguous).  <-- R3 bugfix
// ---------------------------------------------------------------------------
__global__ __launch_bounds__(256, 2) void k3_mfma(const u16* __restrict__ Lu,
                                                  const u16* __restrict__ XT1hi,
                                                  const u16* __restrict__ XT1lo,
                                                  const float* __restrict__ X,
                                                  u16* __restrict__ Yhi,
                                                  u16* __restrict__ Ylo) {
    __shared__ __align__(16) char smem[32768];
    char* Ahi = smem;
    char* Alo = smem + 8192;
    char* Bhi = smem + 16384;
    char* Blo = smem + 24576;
    const int b = blockIdx.z;
    const u16* Au = Lu + (size_t)b * CH * 1024;     // row c: c*1024 hi, +512 lo
    const size_t boff = (size_t)b * CH * NSP;
    const float* Xb = X + boff;
    const int tid = threadIdx.x, lane = tid & 63, w = tid >> 6;
    const int wr = w >> 1, wc = w & 1;
    const int c0 = blockIdx.y * 128, n0 = blockIdx.x * 128;
    const int rl = lane >> 2;
    const int cb = (lane & 3) * 8;
    f32x4 acc[4][4];
#pragma unroll
    for (int i = 0; i < 4; i++)
#pragma unroll
        for (int j = 0; j < 4; j++) acc[i][j] = (f32x4){0.f, 0.f, 0.f, 0.f};

    for (int k0 = 0; k0 < CH; k0 += 32) {
#pragma unroll
        for (int s = 0; s < 2; s++) {
            int idx = w * 2 + s;
            int row = 16 * idx + rl;
            gload16(Au + (size_t)(c0 + row) * 1024 + k0 + cb, Ahi + idx * 1024);
            gload16(Au + (size_t)(c0 + row) * 1024 + 512 + k0 + cb, Alo + idx * 1024);
            gload16(XT1hi + boff + (size_t)(n0 + row) * CH + k0 + cb, Bhi + idx * 1024);
            gload16(XT1lo + boff + (size_t)(n0 + row) * CH + k0 + cb, Blo + idx * 1024);
        }
        __syncthreads();
        bfrag8 ah[4], al[4], bh[4], bl[4];
        const int q16 = (lane >> 4) * 16;
        const int l15 = (lane & 15);
#pragma unroll
        for (int i = 0; i < 4; i++) {
            int offa = (wr * 64 + i * 16 + l15) * 64 + q16;
            ah[i] = *(const bfrag8*)(Ahi + offa);
            al[i] = *(const bfrag8*)(Alo + offa);
            int offb = (wc * 64 + i * 16 + l15) * 64 + q16;
            bh[i] = *(const bfrag8*)(Bhi + offb);
            bl[i] = *(const bfrag8*)(Blo + offb);
        }
#pragma unroll
        for (int i = 0; i < 4; i++)
#pragma unroll
            for (int j = 0; j < 4; j++) {
                acc[i][j] = __builtin_amdgcn_mfma_f32_16x16x32_bf16(ah[i], bh[j], acc[i][j], 0, 0, 0);
                acc[i][j] = __builtin_amdgcn_mfma_f32_16x16x32_bf16(ah[i], bl[j], acc[i][j], 0, 0, 0);
                acc[i][j] = __builtin_amdgcn_mfma_f32_16x16x32_bf16(al[i], bh[j], acc[i][j], 0, 0, 0);
            }
        __syncthreads();
    }
    u16* Yhb = Yhi + boff;
    u16* Ylb = Ylo + boff;
    const int col = lane & 15, qr = (lane >> 4) * 4;
#pragma unroll
    for (int i = 0; i < 4; i++)
#pragma unroll
        for (int j = 0; j < 4; j++)
#pragma unroll
            for (int r = 0; r < 4; r++) {
                int c = c0 + wr * 64 + 16 * i + qr + r;
                int n = n0 + wc * 64 + 16 * j + col;
                float v = acc[i][j][r] + Xb[(size_t)c * NSP + n];
                u16 h, l;
                split_bf16(v, h, l);
                Yhb[(size_t)c * NSP + n] = h;
                Ylb[(size_t)c * NSP + n] = l;
            }
}

// ---------------------------------------------------------------------------
// Stage 2 (unchanged, proven in R2): k4 Gram MFMA, packed softmax 4096,
// k6 MFMA split-K=4, combine.
// ---------------------------------------------------------------------------
__global__ __launch_bounds__(256, 2) void k4_mfma(const u16* __restrict__ YThi,
                                                  const u16* __restrict__ YTlo,
                                                  float* __restrict__ S) {
    __shared__ __align__(16) char smem[32768];
    char* Ahi = smem;
    char* Alo = smem + 8192;
    char* Bhi = smem + 16384;
    char* Blo = smem + 24576;
    const int tid = threadIdx.x, lane = tid & 63, w = tid >> 6;
    const int wr = w >> 1, wc = w & 1;
    const int n0 = blockIdx.y * 128, m0 = blockIdx.x * 128;
    const int rl = lane >> 2;
    const int cb = (lane & 3) * 8;
    f32x4 acc[4][4];
#pragma unroll
    for (int i = 0; i < 4; i++)
#pragma unroll
        for (int j = 0; j < 4; j++) acc[i][j] = (f32x4){0.f, 0.f, 0.f, 0.f};

    for (int k0 = 0; k0 < CH; k0 += 32) {
#pragma unroll
        for (int s = 0; s < 2; s++) {
            int idx = w * 2 + s;
            int row = 16 * idx + rl;
            gload16(YThi + (size_t)(n0 + row) * CH + k0 + cb, Ahi + idx * 1024);
            gload16(YTlo + (size_t)(n0 + row) * CH + k0 + cb, Alo + idx * 1024);
            gload16(YThi + (size_t)(m0 + row) * CH + k0 + cb, Bhi + idx * 1024);
            gload16(YTlo + (size_t)(m0 + row) * CH + k0 + cb, Blo + idx * 1024);
        }
        __syncthreads();
        bfrag8 ah[4], al[4], bh[4], bl[4];
        const int q16 = (lane >> 4) * 16;
        const int l15 = (lane & 15);
#pragma unroll
        for (int i = 0; i < 4; i++) {
            int offa = (wr * 64 + i * 16 + l15) * 64 + q16;
            ah[i] = *(const bfrag8*)(Ahi + offa);
            al[i] = *(const bfrag8*)(Alo + offa);
            int offb = (wc * 64 + i * 16 + l15) * 64 + q16;
            bh[i] = *(const bfrag8*)(Bhi + offb);
            bl[i] = *(const bfrag8*)(Blo + offb);
        }
#pragma unroll
        for (int i = 0; i < 4; i++)
#pragma unroll
            for (int j = 0; j < 4; j++) {
                acc[i][j] = __builtin_amdgcn_mfma_f32_16x16x32_bf16(ah[i], bh[j], acc[i][j], 0, 0, 0);
                acc[i][j] = __builtin_amdgcn_mfma_f32_16x16x32_bf16(ah[i], bl[j], acc[i][j], 0, 0, 0);
                acc[i][j] = __builtin_amdgcn_mfma_f32_16x16x32_bf16(al[i], bh[j], acc[i][j], 0, 0, 0);
            }
        __syncthreads();
    }
    const int col = lane & 15, qr = (lane >> 4) * 4;
#pragma unroll
    for (int i = 0; i < 4; i++)
#pragma unroll
        for (int j = 0; j < 4; j++)
#pragma unroll
            for (int r = 0; r < 4; r++)
                S[(size_t)(n0 + wr * 64 + 16 * i + qr + r) * NSP + m0 + wc * 64 + 16 * j + col] =
                    acc[i][j][r];
}

__global__ __launch_bounds__(256) void k_softmax_pack(float* __restrict__ S) {
    __shared__ float buf[4096];
    __shared__ float red[256];
    const int tid = threadIdx.x;
    float* row = S + (size_t)blockIdx.x * NSP;
    float m = -INFINITY;
#pragma unroll
    for (int it = 0; it < 4; it++) {
        int i = (tid + it * 256) * 4;
        float4 v = *(const float4*)(row + i);
        buf[i] = v.x; buf[i + 1] = v.y; buf[i + 2] = v.z; buf[i + 3] = v.w;
        m = fmaxf(m, fmaxf(fmaxf(v.x, v.y), fmaxf(v.z, v.w)));
    }
    red[tid] = m;
    __syncthreads();
    for (int s = 128; s > 0; s >>= 1) {
        if (tid < s) red[tid] = fmaxf(red[tid], red[tid + s]);
        __syncthreads();
    }
    m = red[0];
    __syncthreads();
    float sum = 0.f;
#pragma unroll
    for (int it = 0; it < 4; it++) {
        int i = (tid + it * 256) * 4;
        float e0 = expf(buf[i] - m), e1 = expf(buf[i + 1] - m);
        float e2 = expf(buf[i + 2] - m), e3 = expf(buf[i + 3] - m);
        buf[i] = e0; buf[i + 1] = e1; buf[i + 2] = e2; buf[i + 3] = e3;
        sum += e0 + e1 + e2 + e3;
    }
    red[tid] = sum;
    __syncthreads();
    for (int s = 128; s > 0; s >>= 1) {
        if (tid < s) red[tid] += red[tid + s];
        __syncthreads();
    }
    float inv = 1.0f / red[0];
    u16* u = (u16*)row;
#pragma unroll
    for (int it = 0; it < 4; it++) {
        int i = (tid + it * 256) * 4;
        ushort4 hv, lv;
        split_bf16(buf[i] * inv, hv.x, lv.x);
        split_bf16(buf[i + 1] * inv, hv.y, lv.y);
        split_bf16(buf[i + 2] * inv, hv.z, lv.z);
        split_bf16(buf[i + 3] * inv, hv.w, lv.w);
        *(ushort4*)(u + i) = hv;
        *(ushort4*)(u + NSP + i) = lv;
    }
}

__global__ __launch_bounds__(256, 2) void k6_mfma(const u16* __restrict__ Yhi,
                                                  const u16* __restrict__ Ylo,
                                                  const u16* __restrict__ Ppk,
                                                  float* __restrict__ Pp) {
    __shared__ __align__(16) char smem[32768];
    char* Ahi = smem;
    char* Alo = smem + 8192;
    char* Bhi = smem + 16384;
    char* Blo = smem + 24576;
    const int tid = threadIdx.x, lane = tid & 63, w = tid >> 6;
    const int wr = w >> 1, wc = w & 1;
    const int m0 = blockIdx.x * 128, c0 = blockIdx.y * 128, z = blockIdx.z;
    const int kb = z * 1024;
    const int rl = lane >> 2;
    const int cb = (lane & 3) * 8;
    f32x4 acc[4][4];
#pragma unroll
    for (int i = 0; i < 4; i++)
#pragma unroll
        for (int j = 0; j < 4; j++) acc[i][j] = (f32x4){0.f, 0.f, 0.f, 0.f};

    for (int k0 = 0; k0 < 1024; k0 += 32) {
        const int kk = kb + k0;
#pragma unroll
        for (int s = 0; s < 2; s++) {
            int idx = w * 2 + s;
            int row = 16 * idx + rl;
            gload16(Yhi + (size_t)(c0 + row) * NSP + kk + cb, Ahi + idx * 1024);
            gload16(Ylo + (size_t)(c0 + row) * NSP + kk + cb, Alo + idx * 1024);
            const u16* pr = Ppk + (size_t)(m0 + row) * 8192;
            gload16(pr + kk + cb, Bhi + idx * 1024);
            gload16(pr + 4096 + kk + cb, Blo + idx * 1024);
        }
        __syncthreads();
        bfrag8 ah[4], al[4], bh[4], bl[4];
        const int q16 = (lane >> 4) * 16;
        const int l15 = (lane & 15);
#pragma unroll
        for (int i = 0; i < 4; i++) {
            int offa = (wr * 64 + i * 16 + l15) * 64 + q16;
            ah[i] = *(const bfrag8*)(Ahi + offa);
            al[i] = *(const bfrag8*)(Alo + offa);
            int offb = (wc * 64 + i * 16 + l15) * 64 + q16;
            bh[i] = *(const bfrag8*)(Bhi + offb);
            bl[i] = *(const bfrag8*)(Blo + offb);
        }
#pragma unroll
        for (int i = 0; i < 4; i++)
#pragma unroll
            for (int j = 0; j < 4; j++) {
                acc[i][j] = __builtin_amdgcn_mfma_f32_16x16x32_bf16(ah[i], bh[j], acc[i][j], 0, 0, 0);
                acc[i][j] = __builtin_amdgcn_mfma_f32_16x16x32_bf16(ah[i], bl[j], acc[i][j], 0, 0, 0);
                acc[i][j] = __builtin_amdgcn_mfma_f32_16x16x32_bf16(al[i], bh[j], acc[i][j], 0, 0, 0);
            }
        __syncthreads();
    }
    float* out = Pp + (size_t)z * CH * NSP;
    const int col = lane & 15, qr = (lane >> 4) * 4;
#pragma unroll
    for (int i = 0; i < 4; i++)
#pragma unroll
        for (int j = 0; j < 4; j++)
#pragma unroll
            for (int r = 0; r < 4; r++)
                out[(size_t)(c0 + wr * 64 + 16 * i + qr + r) * NSP + m0 + wc * 64 + 16 * j + col] =
                    acc[i][j][r];
}

__global__ __launch_bounds__(256) void k_combine(const float* __restrict__ Pp,
                                                 const u16* __restrict__ Yhi,
                                                 const u16* __restrict__ Ylo,
                                                 float* __restrict__ outb) {
    const size_t CN = (size_t)CH * NSP;
    size_t i = ((size_t)blockIdx.x * 256 + threadIdx.x) * 4;
    float4 a = *(const float4*)(Pp + i);
    float4 b = *(const float4*)(Pp + CN + i);
    float4 c = *(const float4*)(Pp + 2 * CN + i);
    float4 d = *(const float4*)(Pp + 3 * CN + i);
    ushort4 h = *(const ushort4*)(Yhi + i);
    ushort4 l = *(const ushort4*)(Ylo + i);
    float4 o;
    o.x = a.x + b.x + c.x + d.x + join_bf16(h.x, l.x);
    o.y = a.y + b.y + c.y + d.y + join_bf16(h.y, l.y);
    o.z = a.z + b.z + c.z + d.z + join_bf16(h.z, l.z);
    o.w = a.w + b.w + c.w + d.w + join_bf16(h.w, l.w);
    *(float4*)(outb + i) = o;
}

extern "C" void kernel_launch(void* const* d_in, const int* in_sizes, int n_in,
                              void* d_out, int out_size, void* d_ws, size_t ws_size,
                              hipStream_t stream) {
    const float* x = (const float*)d_in[0];
    float* out = (float*)d_out;

    // workspace layout (16MB units of SZ16), with aliasing:
    //   [0..6): XHi|XLo|XT2hi|XT2lo|XT1hi|XT1lo  (dead after k3)
    //           S (64MB) aliases [0..4) only, used after stage 1 completes
    //   [6..10): Yhi|Ylo|YThi|YTlo  (live to end)
    //   Lg at 10*SZ16 (4MB); Pp after (32MB).  Total 196 MB (same as R2).
    char* p = (char*)d_ws;
    const size_t SZ16 = (size_t)BATCH * CH * NSP * 2;  // 16 MB
    u16* XHi = (u16*)p;
    u16* XLo = (u16*)(p + SZ16);
    u16* XT2hi = (u16*)(p + 2 * SZ16);
    u16* XT2lo = (u16*)(p + 3 * SZ16);
    u16* XT1hi = (u16*)(p + 4 * SZ16);
    u16* XT1lo = (u16*)(p + 5 * SZ16);
    float* S = (float*)p;  // aliases XHi..XT2lo (dead after k1)
    u16* Yhi = (u16*)(p + 6 * SZ16);
    u16* Ylo = (u16*)(p + 7 * SZ16);
    u16* YThi = (u16*)(p + 8 * SZ16);
    u16* YTlo = (u16*)(p + 9 * SZ16);
    float* Lg = (float*)(p + 10 * SZ16);                               // 4 MB
    float* Pp = (float*)(p + 10 * SZ16 + (size_t)BATCH * CH * CH * 4); // 32 MB

    // Stage 1: channel attention, all MFMA
    k_convert<<<dim3((BATCH * CH * NSP) / (4 * 256)), 256, 0, stream>>>(x, XHi, XLo);
    // pk^T: x flat viewed [N][C] -> XT2 [d][n]
    k_transpose_split<<<dim3(NSP / 64, CH / 64, BATCH), 256, 0, stream>>>(XHi, XLo, XT2hi, XT2lo,
                                                                          NSP, CH);
    // pq^T: x flat viewed [C][N] -> XT1 [n][c]
    k_transpose_split<<<dim3(CH / 64, NSP / 64, BATCH), 256, 0, stream>>>(XHi, XLo, XT1hi, XT1lo,
                                                                          CH, NSP);
    k1_mfma<<<dim3(CH / 128, CH / 128, BATCH), 256, 0, stream>>>(XHi, XLo, XT2hi, XT2lo, Lg);
    k_softmax_pack512<<<dim3(BATCH * CH), 256, 0, stream>>>(Lg);
    k3_mfma<<<dim3(NSP / 128, CH / 128, BATCH), 256, 0, stream>>>((const u16*)Lg, XT1hi, XT1lo, x,
                                                                  Yhi, Ylo);
    // Y split [C][N] -> YT [N][C]
    k_transpose_split<<<dim3(CH / 64, NSP / 64, BATCH), 256, 0, stream>>>(Yhi, Ylo, YThi, YTlo,
                                                                          CH, NSP);

    // Stage 2: positional attention per batch (MFMA) — S aliases dead region
    for (int b = 0; b < BATCH; b++) {
        const u16* YThib = YThi + (size_t)b * NSP * CH;
        const u16* YTlob = YTlo + (size_t)b * NSP * CH;
        const u16* Yhib = Yhi + (size_t)b * CH * NSP;
        const u16* Ylob = Ylo + (size_t)b * CH * NSP;
        k4_mfma<<<dim3(NSP / 128, NSP / 128), 256, 0, stream>>>(YThib, YTlob, S);
        k_softmax_pack<<<dim3(NSP), 256, 0, stream>>>(S);
        k6_mfma<<<dim3(NSP / 128, CH / 128, 4), 256, 0, stream>>>(Yhib, Ylob, (const u16*)S, Pp);
        k_combine<<<dim3((CH * NSP) / (4 * 256)), 256, 0, stream>>>(Pp, Yhib, Ylob,
                                                                    out + (size_t)b * CH * NSP);
    }
}

// Round 5
// 676.476 us; speedup vs baseline: 4.2648x; 1.2239x over previous
//
#include <hip/hip_runtime.h>

#define BATCH 4
#define CH 512
#define NSP 4096   // 64*64 spatial

typedef __attribute__((ext_vector_type(8))) short bfrag8;  // 8 bf16 (4 VGPRs)
typedef __attribute__((ext_vector_type(4))) float f32x4;
typedef unsigned short u16;

#define AS1 __attribute__((address_space(1)))
#define AS3 __attribute__((address_space(3)))
__device__ __forceinline__ void gload16(const void* g, void* l) {
    __builtin_amdgcn_global_load_lds((const AS1 void*)g, (AS3 void*)l, 16, 0, 0);
}

// ---------------------------------------------------------------------------
// split-bf16: y = hi + lo exactly to ~2^-17 relative; fp32 accumulate in MFMA
// ---------------------------------------------------------------------------
__device__ __forceinline__ void split_bf16(float y, u16& h, u16& l) {
    unsigned int u = __float_as_uint(y);
    h = (u16)(u >> 16);
    float r = y - __uint_as_float(((unsigned int)h) << 16);
    l = (u16)(__float_as_uint(r) >> 16);
}
__device__ __forceinline__ float join_bf16(u16 h, u16 l) {
    return __uint_as_float(((unsigned int)h) << 16) + __uint_as_float(((unsigned int)l) << 16);
}

// elementwise: fp32 -> hi/lo bf16 bits (flat; serves [C][N] and [N][C] views)
__global__ __launch_bounds__(256) void k_convert(const float* __restrict__ Y,
                                                 u16* __restrict__ Yhi,
                                                 u16* __restrict__ Ylo) {
    size_t i = ((size_t)blockIdx.x * 256 + threadIdx.x) * 4;
    float4 v = *(const float4*)(Y + i);
    ushort4 h, l;
    split_bf16(v.x, h.x, l.x);
    split_bf16(v.y, h.y, l.y);
    split_bf16(v.z, h.z, l.z);
    split_bf16(v.w, h.w, l.w);
    *(ushort4*)(Yhi + i) = h;
    *(ushort4*)(Ylo + i) = l;
}

// transpose a split pair: src [R][Cc] -> dst [Cc][R] (per-batch stride R*Cc)
__global__ __launch_bounds__(256) void k_transpose_split(const u16* __restrict__ Hs,
                                                         const u16* __restrict__ Ls,
                                                         u16* __restrict__ Hd,
                                                         u16* __restrict__ Ld,
                                                         int R, int Cc) {
    __shared__ unsigned int t[64][65];
    const size_t off = (size_t)blockIdx.z * R * Cc;
    const int r0 = blockIdx.x * 64, c0 = blockIdx.y * 64;
    const int r = threadIdx.x >> 4, col4 = (threadIdx.x & 15) * 4;
#pragma unroll
    for (int it = 0; it < 4; it++) {
        int rl = r + it * 16;
        ushort4 h = *(const ushort4*)(Hs + off + (size_t)(r0 + rl) * Cc + c0 + col4);
        ushort4 l = *(const ushort4*)(Ls + off + (size_t)(r0 + rl) * Cc + c0 + col4);
        t[rl][col4 + 0] = ((unsigned int)h.x << 16) | l.x;
        t[rl][col4 + 1] = ((unsigned int)h.y << 16) | l.y;
        t[rl][col4 + 2] = ((unsigned int)h.z << 16) | l.z;
        t[rl][col4 + 3] = ((unsigned int)h.w << 16) | l.w;
    }
    __syncthreads();
#pragma unroll
    for (int it = 0; it < 4; it++) {
        int cl = r + it * 16;
        unsigned int p0 = t[col4 + 0][cl];
        unsigned int p1 = t[col4 + 1][cl];
        unsigned int p2 = t[col4 + 2][cl];
        unsigned int p3 = t[col4 + 3][cl];
        ushort4 hv, lv;
        hv.x = p0 >> 16; hv.y = p1 >> 16; hv.z = p2 >> 16; hv.w = p3 >> 16;
        lv.x = p0 & 0xffff; lv.y = p1 & 0xffff; lv.z = p2 & 0xffff; lv.w = p3 & 0xffff;
        *(ushort4*)(Hd + off + (size_t)(c0 + cl) * R + r0 + col4) = hv;
        *(ushort4*)(Ld + off + (size_t)(c0 + cl) * R + r0 + col4) = lv;
    }
}

// ---------------------------------------------------------------------------
// k1 MFMA split-K: L_part[kz][c][d] = sum_{n in chunk kz} x[c][n]*pk[n][d].
// blockIdx.z encodes (b, kz): 8 K-chunks of 512. Partials fp32 -> Pk.
// ---------------------------------------------------------------------------
__global__ __launch_bounds__(256, 2) void k1_mfma(const u16* __restrict__ XHi,
                                                  const u16* __restrict__ XLo,
                                                  const u16* __restrict__ XT2hi,
                                                  const u16* __restrict__ XT2lo,
                                                  float* __restrict__ Pk) {
    __shared__ __align__(16) char smem[32768];
    char* Ahi = smem;
    char* Alo = smem + 8192;
    char* Bhi = smem + 16384;
    char* Blo = smem + 24576;
    const int b = blockIdx.z >> 3, kz = blockIdx.z & 7;
    const size_t boff = (size_t)b * CH * NSP;
    const int tid = threadIdx.x, lane = tid & 63, w = tid >> 6;
    const int wr = w >> 1, wc = w & 1;
    const int c0 = blockIdx.y * 128, d0 = blockIdx.x * 128;
    const int rl = lane >> 2;
    const int cb = (lane & 3) * 8;
    f32x4 acc[4][4];
#pragma unroll
    for (int i = 0; i < 4; i++)
#pragma unroll
        for (int j = 0; j < 4; j++) acc[i][j] = (f32x4){0.f, 0.f, 0.f, 0.f};

    const int kbeg = kz * 512, kend = kbeg + 512;
    for (int k0 = kbeg; k0 < kend; k0 += 32) {
#pragma unroll
        for (int s = 0; s < 2; s++) {
            int idx = w * 2 + s;
            int row = 16 * idx + rl;
            gload16(XHi + boff + (size_t)(c0 + row) * NSP + k0 + cb, Ahi + idx * 1024);
            gload16(XLo + boff + (size_t)(c0 + row) * NSP + k0 + cb, Alo + idx * 1024);
            gload16(XT2hi + boff + (size_t)(d0 + row) * NSP + k0 + cb, Bhi + idx * 1024);
            gload16(XT2lo + boff + (size_t)(d0 + row) * NSP + k0 + cb, Blo + idx * 1024);
        }
        __syncthreads();
        bfrag8 ah[4], al[4], bh[4], bl[4];
        const int q16 = (lane >> 4) * 16;
        const int l15 = (lane & 15);
#pragma unroll
        for (int i = 0; i < 4; i++) {
            int offa = (wr * 64 + i * 16 + l15) * 64 + q16;
            ah[i] = *(const bfrag8*)(Ahi + offa);
            al[i] = *(const bfrag8*)(Alo + offa);
            int offb = (wc * 64 + i * 16 + l15) * 64 + q16;
            bh[i] = *(const bfrag8*)(Bhi + offb);
            bl[i] = *(const bfrag8*)(Blo + offb);
        }
#pragma unroll
        for (int i = 0; i < 4; i++)
#pragma unroll
            for (int j = 0; j < 4; j++) {
                acc[i][j] = __builtin_amdgcn_mfma_f32_16x16x32_bf16(ah[i], bh[j], acc[i][j], 0, 0, 0);
                acc[i][j] = __builtin_amdgcn_mfma_f32_16x16x32_bf16(ah[i], bl[j], acc[i][j], 0, 0, 0);
                acc[i][j] = __builtin_amdgcn_mfma_f32_16x16x32_bf16(al[i], bh[j], acc[i][j], 0, 0, 0);
            }
        __syncthreads();
    }
    float* Lb = Pk + (size_t)kz * BATCH * CH * CH + (size_t)b * CH * CH;
    const int col = lane & 15, qr = (lane >> 4) * 4;
#pragma unroll
    for (int i = 0; i < 4; i++)
#pragma unroll
        for (int j = 0; j < 4; j++)
#pragma unroll
            for (int r = 0; r < 4; r++)
                Lb[(size_t)(c0 + wr * 64 + 16 * i + qr + r) * CH + d0 + wc * 64 + 16 * j + col] =
                    acc[i][j][r];
}

// sum 8 split-K partials -> Lg
__global__ __launch_bounds__(256) void k_combine8(const float* __restrict__ Pk,
                                                  float* __restrict__ Lg) {
    const size_t MM = (size_t)BATCH * CH * CH;
    size_t i = ((size_t)blockIdx.x * 256 + threadIdx.x) * 4;
    float4 s = *(const float4*)(Pk + i);
#pragma unroll
    for (int z = 1; z < 8; z++) {
        float4 v = *(const float4*)(Pk + z * MM + i);
        s.x += v.x; s.y += v.y; s.z += v.z; s.w += v.w;
    }
    *(float4*)(Lg + i) = s;
}

// softmax over rows of length 512, writing packed hi/lo bf16 in place:
// row c (512 floats = 1024 u16): [0,512) hi, [512,1024) lo
__global__ __launch_bounds__(256) void k_softmax_pack512(float* __restrict__ Lg) {
    __shared__ float buf[512];
    __shared__ float red[256];
    const int tid = threadIdx.x;
    float* row = Lg + (size_t)blockIdx.x * 512;
    float2 v = *(const float2*)(row + tid * 2);
    buf[tid * 2] = v.x;
    buf[tid * 2 + 1] = v.y;
    red[tid] = fmaxf(v.x, v.y);
    __syncthreads();
    for (int s = 128; s > 0; s >>= 1) {
        if (tid < s) red[tid] = fmaxf(red[tid], red[tid + s]);
        __syncthreads();
    }
    float m = red[0];
    __syncthreads();
    float e0 = expf(buf[tid * 2] - m), e1 = expf(buf[tid * 2 + 1] - m);
    buf[tid * 2] = e0;
    buf[tid * 2 + 1] = e1;
    red[tid] = e0 + e1;
    __syncthreads();
    for (int s = 128; s > 0; s >>= 1) {
        if (tid < s) red[tid] += red[tid + s];
        __syncthreads();
    }
    float inv = 1.0f / red[0];
    u16* u = (u16*)row;
    u16 h0, l0, h1, l1;
    split_bf16(buf[tid * 2] * inv, h0, l0);
    split_bf16(buf[tid * 2 + 1] * inv, h1, l1);
    __syncthreads();  // all reads of row done before overwrite
    u[tid * 2] = h0;
    u[tid * 2 + 1] = h1;
    u[512 + tid * 2] = l0;
    u[512 + tid * 2 + 1] = l1;
}

// ---------------------------------------------------------------------------
// k3 MFMA: Y[c][n] = sum_d A[c][d] * pq[d][n] + x[c][n]; writes Yhi/Ylo split.
// A = packed softmax rows (len 512); B = XT1 [n][c] = pq^T.
// ---------------------------------------------------------------------------
__global__ __launch_bounds__(256, 2) void k3_mfma(const u16* __restrict__ Lu,
                                                  const u16* __restrict__ XT1hi,
                                                  const u16* __restrict__ XT1lo,
                                                  const float* __restrict__ X,
                                                  u16* __restrict__ Yhi,
                                                  u16* __restrict__ Ylo) {
    __shared__ __align__(16) char smem[32768];
    char* Ahi = smem;
    char* Alo = smem + 8192;
    char* Bhi = smem + 16384;
    char* Blo = smem + 24576;
    const int b = blockIdx.z;
    const u16* Au = Lu + (size_t)b * CH * 1024;     // row c: c*1024 hi, +512 lo
    const size_t boff = (size_t)b * CH * NSP;
    const float* Xb = X + boff;
    const int tid = threadIdx.x, lane = tid & 63, w = tid >> 6;
    const int wr = w >> 1, wc = w & 1;
    const int c0 = blockIdx.y * 128, n0 = blockIdx.x * 128;
    const int rl = lane >> 2;
    const int cb = (lane & 3) * 8;
    f32x4 acc[4][4];
#pragma unroll
    for (int i = 0; i < 4; i++)
#pragma unroll
        for (int j = 0; j < 4; j++) acc[i][j] = (f32x4){0.f, 0.f, 0.f, 0.f};

    for (int k0 = 0; k0 < CH; k0 += 32) {
#pragma unroll
        for (int s = 0; s < 2; s++) {
            int idx = w * 2 + s;
            int row = 16 * idx + rl;
            gload16(Au + (size_t)(c0 + row) * 1024 + k0 + cb, Ahi + idx * 1024);
            gload16(Au + (size_t)(c0 + row) * 1024 + 512 + k0 + cb, Alo + idx * 1024);
            gload16(XT1hi + boff + (size_t)(n0 + row) * CH + k0 + cb, Bhi + idx * 1024);
            gload16(XT1lo + boff + (size_t)(n0 + row) * CH + k0 + cb, Blo + idx * 1024);
        }
        __syncthreads();
        bfrag8 ah[4], al[4], bh[4], bl[4];
        const int q16 = (lane >> 4) * 16;
        const int l15 = (lane & 15);
#pragma unroll
        for (int i = 0; i < 4; i++) {
            int offa = (wr * 64 + i * 16 + l15) * 64 + q16;
            ah[i] = *(const bfrag8*)(Ahi + offa);
            al[i] = *(const bfrag8*)(Alo + offa);
            int offb = (wc * 64 + i * 16 + l15) * 64 + q16;
            bh[i] = *(const bfrag8*)(Bhi + offb);
            bl[i] = *(const bfrag8*)(Blo + offb);
        }
#pragma unroll
        for (int i = 0; i < 4; i++)
#pragma unroll
            for (int j = 0; j < 4; j++) {
                acc[i][j] = __builtin_amdgcn_mfma_f32_16x16x32_bf16(ah[i], bh[j], acc[i][j], 0, 0, 0);
                acc[i][j] = __builtin_amdgcn_mfma_f32_16x16x32_bf16(ah[i], bl[j], acc[i][j], 0, 0, 0);
                acc[i][j] = __builtin_amdgcn_mfma_f32_16x16x32_bf16(al[i], bh[j], acc[i][j], 0, 0, 0);
            }
        __syncthreads();
    }
    u16* Yhb = Yhi + boff;
    u16* Ylb = Ylo + boff;
    const int col = lane & 15, qr = (lane >> 4) * 4;
#pragma unroll
    for (int i = 0; i < 4; i++)
#pragma unroll
        for (int j = 0; j < 4; j++)
#pragma unroll
            for (int r = 0; r < 4; r++) {
                int c = c0 + wr * 64 + 16 * i + qr + r;
                int n = n0 + wc * 64 + 16 * j + col;
                float v = acc[i][j][r] + Xb[(size_t)c * NSP + n];
                u16 h, l;
                split_bf16(v, h, l);
                Yhb[(size_t)c * NSP + n] = h;
                Ylb[(size_t)c * NSP + n] = l;
            }
}

// ---------------------------------------------------------------------------
// k4 MFMA symmetric: S = Y^T Y. Triangular grid (528 blocks, tiles j<=i).
// Off-diagonal blocks also write the mirror tile via padded-LDS transpose.
// ---------------------------------------------------------------------------
__global__ __launch_bounds__(256, 2) void k4_mfma(const u16* __restrict__ YThi,
                                                  const u16* __restrict__ YTlo,
                                                  float* __restrict__ S) {
    __shared__ __align__(16) char smem[34816];  // 32KB staging; 2x(64x68 f32) transpose
    char* Ahi = smem;
    char* Alo = smem + 8192;
    char* Bhi = smem + 16384;
    char* Blo = smem + 24576;
    const int tid = threadIdx.x, lane = tid & 63, w = tid >> 6;
    const int wr = w >> 1, wc = w & 1;
    // triangular decode: block idx -> (bi, bj), bj <= bi
    int idx = blockIdx.x;
    int bi = (int)((sqrtf(8.f * (float)idx + 1.f) - 1.f) * 0.5f);
    while ((bi + 1) * (bi + 2) / 2 <= idx) bi++;
    while (bi * (bi + 1) / 2 > idx) bi--;
    int bj = idx - bi * (bi + 1) / 2;
    const int n0 = bi * 128, m0 = bj * 128;
    const bool diag = (bi == bj);
    const int rl = lane >> 2;
    const int cb = (lane & 3) * 8;
    f32x4 acc[4][4];
#pragma unroll
    for (int i = 0; i < 4; i++)
#pragma unroll
        for (int j = 0; j < 4; j++) acc[i][j] = (f32x4){0.f, 0.f, 0.f, 0.f};

    for (int k0 = 0; k0 < CH; k0 += 32) {
#pragma unroll
        for (int s = 0; s < 2; s++) {
            int i2 = w * 2 + s;
            int row = 16 * i2 + rl;
            gload16(YThi + (size_t)(n0 + row) * CH + k0 + cb, Ahi + i2 * 1024);
            gload16(YTlo + (size_t)(n0 + row) * CH + k0 + cb, Alo + i2 * 1024);
            gload16(YThi + (size_t)(m0 + row) * CH + k0 + cb, Bhi + i2 * 1024);
            gload16(YTlo + (size_t)(m0 + row) * CH + k0 + cb, Blo + i2 * 1024);
        }
        __syncthreads();
        bfrag8 ah[4], al[4], bh[4], bl[4];
        const int q16 = (lane >> 4) * 16;
        const int l15 = (lane & 15);
#pragma unroll
        for (int i = 0; i < 4; i++) {
            int offa = (wr * 64 + i * 16 + l15) * 64 + q16;
            ah[i] = *(const bfrag8*)(Ahi + offa);
            al[i] = *(const bfrag8*)(Alo + offa);
            int offb = (wc * 64 + i * 16 + l15) * 64 + q16;
            bh[i] = *(const bfrag8*)(Bhi + offb);
            bl[i] = *(const bfrag8*)(Blo + offb);
        }
#pragma unroll
        for (int i = 0; i < 4; i++)
#pragma unroll
            for (int j = 0; j < 4; j++) {
                acc[i][j] = __builtin_amdgcn_mfma_f32_16x16x32_bf16(ah[i], bh[j], acc[i][j], 0, 0, 0);
                acc[i][j] = __builtin_amdgcn_mfma_f32_16x16x32_bf16(ah[i], bl[j], acc[i][j], 0, 0, 0);
                acc[i][j] = __builtin_amdgcn_mfma_f32_16x16x32_bf16(al[i], bh[j], acc[i][j], 0, 0, 0);
            }
        __syncthreads();
    }
    const int col = lane & 15, qr = (lane >> 4) * 4;
    // normal (lower-triangle) tile write
#pragma unroll
    for (int i = 0; i < 4; i++)
#pragma unroll
        for (int j = 0; j < 4; j++)
#pragma unroll
            for (int r = 0; r < 4; r++)
                S[(size_t)(n0 + wr * 64 + 16 * i + qr + r) * NSP + m0 + wc * 64 + 16 * j + col] =
                    acc[i][j][r];
    if (!diag) {
        // mirror write: S[m][n] = acc, transposed through LDS (two 2-wave rounds).
        // T row stride 68 floats: write banks 2-way (free), read float4-aligned.
        float* Tbase = (float*)smem;
#pragma unroll
        for (int round = 0; round < 2; round++) {
            if (wr == round) {
                float* T = Tbase + wc * (64 * 68);
#pragma unroll
                for (int i = 0; i < 4; i++)
#pragma unroll
                    for (int j = 0; j < 4; j++)
#pragma unroll
                        for (int r = 0; r < 4; r++)
                            T[(16 * j + col) * 68 + 16 * i + qr + r] = acc[i][j][r];
            }
            __syncthreads();
            if (wr == round) {
                float* T = Tbase + wc * (64 * 68);
                const int rq = (lane & 15) * 4;      // n-offset within quadrant
#pragma unroll
                for (int rep = 0; rep < 16; rep++) {
                    int cq = rep * 4 + (lane >> 4);  // m-offset within quadrant
                    float4 v = *(const float4*)(T + cq * 68 + rq);
                    *(float4*)(S + (size_t)(m0 + wc * 64 + cq) * NSP + n0 + wr * 64 + rq) = v;
                }
            }
            __syncthreads();
        }
    }
}

__global__ __launch_bounds__(256) void k_softmax_pack(float* __restrict__ S) {
    __shared__ float buf[4096];
    __shared__ float red[256];
    const int tid = threadIdx.x;
    float* row = S + (size_t)blockIdx.x * NSP;
    float m = -INFINITY;
#pragma unroll
    for (int it = 0; it < 4; it++) {
        int i = (tid + it * 256) * 4;
        float4 v = *(const float4*)(row + i);
        buf[i] = v.x; buf[i + 1] = v.y; buf[i + 2] = v.z; buf[i + 3] = v.w;
        m = fmaxf(m, fmaxf(fmaxf(v.x, v.y), fmaxf(v.z, v.w)));
    }
    red[tid] = m;
    __syncthreads();
    for (int s = 128; s > 0; s >>= 1) {
        if (tid < s) red[tid] = fmaxf(red[tid], red[tid + s]);
        __syncthreads();
    }
    m = red[0];
    __syncthreads();
    float sum = 0.f;
#pragma unroll
    for (int it = 0; it < 4; it++) {
        int i = (tid + it * 256) * 4;
        float e0 = expf(buf[i] - m), e1 = expf(buf[i + 1] - m);
        float e2 = expf(buf[i + 2] - m), e3 = expf(buf[i + 3] - m);
        buf[i] = e0; buf[i + 1] = e1; buf[i + 2] = e2; buf[i + 3] = e3;
        sum += e0 + e1 + e2 + e3;
    }
    red[tid] = sum;
    __syncthreads();
    for (int s = 128; s > 0; s >>= 1) {
        if (tid < s) red[tid] += red[tid + s];
        __syncthreads();
    }
    float inv = 1.0f / red[0];
    u16* u = (u16*)row;
#pragma unroll
    for (int it = 0; it < 4; it++) {
        int i = (tid + it * 256) * 4;
        ushort4 hv, lv;
        split_bf16(buf[i] * inv, hv.x, lv.x);
        split_bf16(buf[i + 1] * inv, hv.y, lv.y);
        split_bf16(buf[i + 2] * inv, hv.z, lv.z);
        split_bf16(buf[i + 3] * inv, hv.w, lv.w);
        *(ushort4*)(u + i) = hv;
        *(ushort4*)(u + NSP + i) = lv;
    }
}

__global__ __launch_bounds__(256, 2) void k6_mfma(const u16* __restrict__ Yhi,
                                                  const u16* __restrict__ Ylo,
                                                  const u16* __restrict__ Ppk,
                                                  float* __restrict__ Pp) {
    __shared__ __align__(16) char smem[32768];
    char* Ahi = smem;
    char* Alo = smem + 8192;
    char* Bhi = smem + 16384;
    char* Blo = smem + 24576;
    const int tid = threadIdx.x, lane = tid & 63, w = tid >> 6;
    const int wr = w >> 1, wc = w & 1;
    const int m0 = blockIdx.x * 128, c0 = blockIdx.y * 128, z = blockIdx.z;
    const int kb = z * 1024;
    const int rl = lane >> 2;
    const int cb = (lane & 3) * 8;
    f32x4 acc[4][4];
#pragma unroll
    for (int i = 0; i < 4; i++)
#pragma unroll
        for (int j = 0; j < 4; j++) acc[i][j] = (f32x4){0.f, 0.f, 0.f, 0.f};

    for (int k0 = 0; k0 < 1024; k0 += 32) {
        const int kk = kb + k0;
#pragma unroll
        for (int s = 0; s < 2; s++) {
            int idx = w * 2 + s;
            int row = 16 * idx + rl;
            gload16(Yhi + (size_t)(c0 + row) * NSP + kk + cb, Ahi + idx * 1024);
            gload16(Ylo + (size_t)(c0 + row) * NSP + kk + cb, Alo + idx * 1024);
            const u16* pr = Ppk + (size_t)(m0 + row) * 8192;
            gload16(pr + kk + cb, Bhi + idx * 1024);
            gload16(pr + 4096 + kk + cb, Blo + idx * 1024);
        }
        __syncthreads();
        bfrag8 ah[4], al[4], bh[4], bl[4];
        const int q16 = (lane >> 4) * 16;
        const int l15 = (lane & 15);
#pragma unroll
        for (int i = 0; i < 4; i++) {
            int offa = (wr * 64 + i * 16 + l15) * 64 + q16;
            ah[i] = *(const bfrag8*)(Ahi + offa);
            al[i] = *(const bfrag8*)(Alo + offa);
            int offb = (wc * 64 + i * 16 + l15) * 64 + q16;
            bh[i] = *(const bfrag8*)(Bhi + offb);
            bl[i] = *(const bfrag8*)(Blo + offb);
        }
#pragma unroll
        for (int i = 0; i < 4; i++)
#pragma unroll
            for (int j = 0; j < 4; j++) {
                acc[i][j] = __builtin_amdgcn_mfma_f32_16x16x32_bf16(ah[i], bh[j], acc[i][j], 0, 0, 0);
                acc[i][j] = __builtin_amdgcn_mfma_f32_16x16x32_bf16(ah[i], bl[j], acc[i][j], 0, 0, 0);
                acc[i][j] = __builtin_amdgcn_mfma_f32_16x16x32_bf16(al[i], bh[j], acc[i][j], 0, 0, 0);
            }
        __syncthreads();
    }
    float* out = Pp + (size_t)z * CH * NSP;
    const int col = lane & 15, qr = (lane >> 4) * 4;
#pragma unroll
    for (int i = 0; i < 4; i++)
#pragma unroll
        for (int j = 0; j < 4; j++)
#pragma unroll
            for (int r = 0; r < 4; r++)
                out[(size_t)(c0 + wr * 64 + 16 * i + qr + r) * NSP + m0 + wc * 64 + 16 * j + col] =
                    acc[i][j][r];
}

__global__ __launch_bounds__(256) void k_combine(const float* __restrict__ Pp,
                                                 const u16* __restrict__ Yhi,
                                                 const u16* __restrict__ Ylo,
                                                 float* __restrict__ outb) {
    const size_t CN = (size_t)CH * NSP;
    size_t i = ((size_t)blockIdx.x * 256 + threadIdx.x) * 4;
    float4 a = *(const float4*)(Pp + i);
    float4 b = *(const float4*)(Pp + CN + i);
    float4 c = *(const float4*)(Pp + 2 * CN + i);
    float4 d = *(const float4*)(Pp + 3 * CN + i);
    ushort4 h = *(const ushort4*)(Yhi + i);
    ushort4 l = *(const ushort4*)(Ylo + i);
    float4 o;
    o.x = a.x + b.x + c.x + d.x + join_bf16(h.x, l.x);
    o.y = a.y + b.y + c.y + d.y + join_bf16(h.y, l.y);
    o.z = a.z + b.z + c.z + d.z + join_bf16(h.z, l.z);
    o.w = a.w + b.w + c.w + d.w + join_bf16(h.w, l.w);
    *(float4*)(outb + i) = o;
}

extern "C" void kernel_launch(void* const* d_in, const int* in_sizes, int n_in,
                              void* d_out, int out_size, void* d_ws, size_t ws_size,
                              hipStream_t stream) {
    const float* x = (const float*)d_in[0];
    float* out = (float*)d_out;

    // workspace layout (16MB units of SZ16), with aliasing:
    //   [0..6): XHi|XLo|XT2hi|XT2lo|XT1hi|XT1lo  (dead after k3)
    //           S (64MB) aliases [0..4), used after stage 1 completes
    //   [6..10): Yhi|Ylo|YThi|YTlo  (live to end)
    //   Lg at 10*SZ16 (4MB); Pp after (32MB; also k1 split-K partials).
    char* p = (char*)d_ws;
    const size_t SZ16 = (size_t)BATCH * CH * NSP * 2;  // 16 MB
    u16* XHi = (u16*)p;
    u16* XLo = (u16*)(p + SZ16);
    u16* XT2hi = (u16*)(p + 2 * SZ16);
    u16* XT2lo = (u16*)(p + 3 * SZ16);
    u16* XT1hi = (u16*)(p + 4 * SZ16);
    u16* XT1lo = (u16*)(p + 5 * SZ16);
    float* S = (float*)p;  // aliases XHi..XT2lo (dead after k1)
    u16* Yhi = (u16*)(p + 6 * SZ16);
    u16* Ylo = (u16*)(p + 7 * SZ16);
    u16* YThi = (u16*)(p + 8 * SZ16);
    u16* YTlo = (u16*)(p + 9 * SZ16);
    float* Lg = (float*)(p + 10 * SZ16);                               // 4 MB
    float* Pp = (float*)(p + 10 * SZ16 + (size_t)BATCH * CH * CH * 4); // 32 MB

    // Stage 1: channel attention, all MFMA
    k_convert<<<dim3((BATCH * CH * NSP) / (4 * 256)), 256, 0, stream>>>(x, XHi, XLo);
    // pk^T: x flat viewed [N][C] -> XT2 [d][n]
    k_transpose_split<<<dim3(NSP / 64, CH / 64, BATCH), 256, 0, stream>>>(XHi, XLo, XT2hi, XT2lo,
                                                                          NSP, CH);
    // pq^T: x flat viewed [C][N] -> XT1 [n][c]
    k_transpose_split<<<dim3(CH / 64, NSP / 64, BATCH), 256, 0, stream>>>(XHi, XLo, XT1hi, XT1lo,
                                                                          CH, NSP);
    // k1 split-K=8: partials into Pp, then combine into Lg
    k1_mfma<<<dim3(CH / 128, CH / 128, BATCH * 8), 256, 0, stream>>>(XHi, XLo, XT2hi, XT2lo, Pp);
    k_combine8<<<dim3((BATCH * CH * CH) / (4 * 256)), 256, 0, stream>>>(Pp, Lg);
    k_softmax_pack512<<<dim3(BATCH * CH), 256, 0, stream>>>(Lg);
    k3_mfma<<<dim3(NSP / 128, CH / 128, BATCH), 256, 0, stream>>>((const u16*)Lg, XT1hi, XT1lo, x,
                                                                  Yhi, Ylo);
    // Y split [C][N] -> YT [N][C]
    k_transpose_split<<<dim3(CH / 64, NSP / 64, BATCH), 256, 0, stream>>>(Yhi, Ylo, YThi, YTlo,
                                                                          CH, NSP);

    // Stage 2: positional attention per batch (MFMA) — S aliases dead region
    const int TRI = (NSP / 128) * (NSP / 128 + 1) / 2;  // 528 triangular tiles
    for (int b = 0; b < BATCH; b++) {
        const u16* YThib = YThi + (size_t)b * NSP * CH;
        const u16* YTlob = YTlo + (size_t)b * NSP * CH;
        const u16* Yhib = Yhi + (size_t)b * CH * NSP;
        const u16* Ylob = Ylo + (size_t)b * CH * NSP;
        k4_mfma<<<dim3(TRI), 256, 0, stream>>>(YThib, YTlob, S);
        k_softmax_pack<<<dim3(NSP), 256, 0, stream>>>(S);
        k6_mfma<<<dim3(NSP / 128, CH / 128, 4), 256, 0, stream>>>(Yhib, Ylob, (const u16*)S, Pp);
        k_combine<<<dim3((CH * NSP) / (4 * 256)), 256, 0, stream>>>(Pp, Yhib, Ylob,
                                                                    out + (size_t)b * CH * NSP);
    }
}

// Round 6
// 601.899 us; speedup vs baseline: 4.7932x; 1.1239x over previous
//
#include <hip/hip_runtime.h>

#define BATCH 4
#define CH 512
#define NSP 4096   // 64*64 spatial

typedef __attribute__((ext_vector_type(8))) short bfrag8;  // 8 bf16 (4 VGPRs)
typedef __attribute__((ext_vector_type(4))) float f32x4;
typedef unsigned short u16;

#define AS1 __attribute__((address_space(1)))
#define AS3 __attribute__((address_space(3)))
__device__ __forceinline__ void gload16(const void* g, void* l) {
    __builtin_amdgcn_global_load_lds((const AS1 void*)g, (AS3 void*)l, 16, 0, 0);
}

__device__ __forceinline__ void split_bf16(float y, u16& h, u16& l) {
    unsigned int u = __float_as_uint(y);
    h = (u16)(u >> 16);
    float r = y - __uint_as_float(((unsigned int)h) << 16);
    l = (u16)(__float_as_uint(r) >> 16);
}
__device__ __forceinline__ float join_bf16(u16 h, u16 l) {
    return __uint_as_float(((unsigned int)h) << 16) + __uint_as_float(((unsigned int)l) << 16);
}

// ---------------------------------------------------------------------------
// Fused prep 1: read x via [C][N] view; write XHi/XLo (same layout) AND
// XT1 [n][c] (transpose) through LDS.  grid (NSP/64, CH/64, BATCH)
// ---------------------------------------------------------------------------
__global__ __launch_bounds__(256) void k_prep_cn(const float* __restrict__ X,
                                                 u16* __restrict__ XHi,
                                                 u16* __restrict__ XLo,
                                                 u16* __restrict__ XT1hi,
                                                 u16* __restrict__ XT1lo) {
    __shared__ unsigned int t[64][65];
    const size_t boff = (size_t)blockIdx.z * CH * NSP;
    const int c0 = blockIdx.y * 64, n0 = blockIdx.x * 64;
    const int r = threadIdx.x >> 4, col4 = (threadIdx.x & 15) * 4;
#pragma unroll
    for (int it = 0; it < 4; it++) {
        int rl = r + it * 16;
        float4 v = *(const float4*)(X + boff + (size_t)(c0 + rl) * NSP + n0 + col4);
        ushort4 h, l;
        split_bf16(v.x, h.x, l.x);
        split_bf16(v.y, h.y, l.y);
        split_bf16(v.z, h.z, l.z);
        split_bf16(v.w, h.w, l.w);
        *(ushort4*)(XHi + boff + (size_t)(c0 + rl) * NSP + n0 + col4) = h;
        *(ushort4*)(XLo + boff + (size_t)(c0 + rl) * NSP + n0 + col4) = l;
        t[rl][col4 + 0] = ((unsigned int)h.x << 16) | l.x;
        t[rl][col4 + 1] = ((unsigned int)h.y << 16) | l.y;
        t[rl][col4 + 2] = ((unsigned int)h.z << 16) | l.z;
        t[rl][col4 + 3] = ((unsigned int)h.w << 16) | l.w;
    }
    __syncthreads();
#pragma unroll
    for (int it = 0; it < 4; it++) {
        int cl = r + it * 16;  // n within tile
        unsigned int p0 = t[col4 + 0][cl];
        unsigned int p1 = t[col4 + 1][cl];
        unsigned int p2 = t[col4 + 2][cl];
        unsigned int p3 = t[col4 + 3][cl];
        ushort4 hv, lv;
        hv.x = p0 >> 16; hv.y = p1 >> 16; hv.z = p2 >> 16; hv.w = p3 >> 16;
        lv.x = p0 & 0xffff; lv.y = p1 & 0xffff; lv.z = p2 & 0xffff; lv.w = p3 & 0xffff;
        *(ushort4*)(XT1hi + boff + (size_t)(n0 + cl) * CH + c0 + col4) = hv;
        *(ushort4*)(XT1lo + boff + (size_t)(n0 + cl) * CH + c0 + col4) = lv;
    }
}

// ---------------------------------------------------------------------------
// Prep 2: read x via [N][C] view; write XT2 [d][n] (transpose) only.
// grid (NSP/64, CH/64, BATCH): blockIdx.x tiles n, blockIdx.y tiles d.
// ---------------------------------------------------------------------------
__global__ __launch_bounds__(256) void k_prep_nc(const float* __restrict__ X,
                                                 u16* __restrict__ XT2hi,
                                                 u16* __restrict__ XT2lo) {
    __shared__ unsigned int t[64][65];
    const size_t boff = (size_t)blockIdx.z * CH * NSP;
    const int n0 = blockIdx.x * 64, d0 = blockIdx.y * 64;
    const int r = threadIdx.x >> 4, col4 = (threadIdx.x & 15) * 4;
#pragma unroll
    for (int it = 0; it < 4; it++) {
        int rl = r + it * 16;  // n within tile
        float4 v = *(const float4*)(X + boff + (size_t)(n0 + rl) * CH + d0 + col4);
        ushort4 h, l;
        split_bf16(v.x, h.x, l.x);
        split_bf16(v.y, h.y, l.y);
        split_bf16(v.z, h.z, l.z);
        split_bf16(v.w, h.w, l.w);
        t[rl][col4 + 0] = ((unsigned int)h.x << 16) | l.x;
        t[rl][col4 + 1] = ((unsigned int)h.y << 16) | l.y;
        t[rl][col4 + 2] = ((unsigned int)h.z << 16) | l.z;
        t[rl][col4 + 3] = ((unsigned int)h.w << 16) | l.w;
    }
    __syncthreads();
#pragma unroll
    for (int it = 0; it < 4; it++) {
        int cl = r + it * 16;  // d within tile
        unsigned int p0 = t[col4 + 0][cl];
        unsigned int p1 = t[col4 + 1][cl];
        unsigned int p2 = t[col4 + 2][cl];
        unsigned int p3 = t[col4 + 3][cl];
        ushort4 hv, lv;
        hv.x = p0 >> 16; hv.y = p1 >> 16; hv.z = p2 >> 16; hv.w = p3 >> 16;
        lv.x = p0 & 0xffff; lv.y = p1 & 0xffff; lv.z = p2 & 0xffff; lv.w = p3 & 0xffff;
        *(ushort4*)(XT2hi + boff + (size_t)(d0 + cl) * NSP + n0 + col4) = hv;
        *(ushort4*)(XT2lo + boff + (size_t)(d0 + cl) * NSP + n0 + col4) = lv;
    }
}

// transpose a split pair: src [R][Cc] -> dst [Cc][R] (per-batch stride R*Cc)
__global__ __launch_bounds__(256) void k_transpose_split(const u16* __restrict__ Hs,
                                                         const u16* __restrict__ Ls,
                                                         u16* __restrict__ Hd,
                                                         u16* __restrict__ Ld,
                                                         int R, int Cc) {
    __shared__ unsigned int t[64][65];
    const size_t off = (size_t)blockIdx.z * R * Cc;
    const int r0 = blockIdx.x * 64, c0 = blockIdx.y * 64;
    const int r = threadIdx.x >> 4, col4 = (threadIdx.x & 15) * 4;
#pragma unroll
    for (int it = 0; it < 4; it++) {
        int rl = r + it * 16;
        ushort4 h = *(const ushort4*)(Hs + off + (size_t)(r0 + rl) * Cc + c0 + col4);
        ushort4 l = *(const ushort4*)(Ls + off + (size_t)(r0 + rl) * Cc + c0 + col4);
        t[rl][col4 + 0] = ((unsigned int)h.x << 16) | l.x;
        t[rl][col4 + 1] = ((unsigned int)h.y << 16) | l.y;
        t[rl][col4 + 2] = ((unsigned int)h.z << 16) | l.z;
        t[rl][col4 + 3] = ((unsigned int)h.w << 16) | l.w;
    }
    __syncthreads();
#pragma unroll
    for (int it = 0; it < 4; it++) {
        int cl = r + it * 16;
        unsigned int p0 = t[col4 + 0][cl];
        unsigned int p1 = t[col4 + 1][cl];
        unsigned int p2 = t[col4 + 2][cl];
        unsigned int p3 = t[col4 + 3][cl];
        ushort4 hv, lv;
        hv.x = p0 >> 16; hv.y = p1 >> 16; hv.z = p2 >> 16; hv.w = p3 >> 16;
        lv.x = p0 & 0xffff; lv.y = p1 & 0xffff; lv.z = p2 & 0xffff; lv.w = p3 & 0xffff;
        *(ushort4*)(Hd + off + (size_t)(c0 + cl) * R + r0 + col4) = hv;
        *(ushort4*)(Ld + off + (size_t)(c0 + cl) * R + r0 + col4) = lv;
    }
}

// ---------------------------------------------------------------------------
// k1 MFMA split-K with XCD swizzle. 1D grid of 512 blocks:
// xcd=bid&7 gets 4 (b,kz) groups; each group = 16 tiles, ~2MB working set
// (fits 4MB XCD L2). Partials fp32 -> Pk.
// ---------------------------------------------------------------------------
__global__ __launch_bounds__(256, 2) void k1_mfma(const u16* __restrict__ XHi,
                                                  const u16* __restrict__ XLo,
                                                  const u16* __restrict__ XT2hi,
                                                  const u16* __restrict__ XT2lo,
                                                  float* __restrict__ Pk) {
    __shared__ __align__(16) char smem[32768];
    char* Ahi = smem;
    char* Alo = smem + 8192;
    char* Bhi = smem + 16384;
    char* Blo = smem + 24576;
    // swizzled decode
    const int bid = blockIdx.x;
    const int xcd = bid & 7;
    const int i1 = bid >> 3;                 // 0..63
    const int group = xcd * 4 + (i1 >> 4);   // 0..31
    const int b = group >> 3, kz = group & 7;
    const int tile = i1 & 15;
    const int c0 = (tile >> 2) * 128, d0 = (tile & 3) * 128;
    const size_t boff = (size_t)b * CH * NSP;
    const int tid = threadIdx.x, lane = tid & 63, w = tid >> 6;
    const int wr = w >> 1, wc = w & 1;
    const int rl = lane >> 2;
    const int cb = (lane & 3) * 8;
    f32x4 acc[4][4];
#pragma unroll
    for (int i = 0; i < 4; i++)
#pragma unroll
        for (int j = 0; j < 4; j++) acc[i][j] = (f32x4){0.f, 0.f, 0.f, 0.f};

    const int kbeg = kz * 512, kend = kbeg + 512;
    for (int k0 = kbeg; k0 < kend; k0 += 32) {
#pragma unroll
        for (int s = 0; s < 2; s++) {
            int idx = w * 2 + s;
            int row = 16 * idx + rl;
            gload16(XHi + boff + (size_t)(c0 + row) * NSP + k0 + cb, Ahi + idx * 1024);
            gload16(XLo + boff + (size_t)(c0 + row) * NSP + k0 + cb, Alo + idx * 1024);
            gload16(XT2hi + boff + (size_t)(d0 + row) * NSP + k0 + cb, Bhi + idx * 1024);
            gload16(XT2lo + boff + (size_t)(d0 + row) * NSP + k0 + cb, Blo + idx * 1024);
        }
        __syncthreads();
        bfrag8 ah[4], al[4], bh[4], bl[4];
        const int q16 = (lane >> 4) * 16;
        const int l15 = (lane & 15);
#pragma unroll
        for (int i = 0; i < 4; i++) {
            int offa = (wr * 64 + i * 16 + l15) * 64 + q16;
            ah[i] = *(const bfrag8*)(Ahi + offa);
            al[i] = *(const bfrag8*)(Alo + offa);
            int offb = (wc * 64 + i * 16 + l15) * 64 + q16;
            bh[i] = *(const bfrag8*)(Bhi + offb);
            bl[i] = *(const bfrag8*)(Blo + offb);
        }
#pragma unroll
        for (int i = 0; i < 4; i++)
#pragma unroll
            for (int j = 0; j < 4; j++) {
                acc[i][j] = __builtin_amdgcn_mfma_f32_16x16x32_bf16(ah[i], bh[j], acc[i][j], 0, 0, 0);
                acc[i][j] = __builtin_amdgcn_mfma_f32_16x16x32_bf16(ah[i], bl[j], acc[i][j], 0, 0, 0);
                acc[i][j] = __builtin_amdgcn_mfma_f32_16x16x32_bf16(al[i], bh[j], acc[i][j], 0, 0, 0);
            }
        __syncthreads();
    }
    float* Lb = Pk + (size_t)kz * BATCH * CH * CH + (size_t)b * CH * CH;
    const int col = lane & 15, qr = (lane >> 4) * 4;
#pragma unroll
    for (int i = 0; i < 4; i++)
#pragma unroll
        for (int j = 0; j < 4; j++)
#pragma unroll
            for (int r = 0; r < 4; r++)
                Lb[(size_t)(c0 + wr * 64 + 16 * i + qr + r) * CH + d0 + wc * 64 + 16 * j + col] =
                    acc[i][j][r];
}

// sum 8 split-K partials -> Lg
__global__ __launch_bounds__(256) void k_combine8(const float* __restrict__ Pk,
                                                  float* __restrict__ Lg) {
    const size_t MM = (size_t)BATCH * CH * CH;
    size_t i = ((size_t)blockIdx.x * 256 + threadIdx.x) * 4;
    float4 s = *(const float4*)(Pk + i);
#pragma unroll
    for (int z = 1; z < 8; z++) {
        float4 v = *(const float4*)(Pk + z * MM + i);
        s.x += v.x; s.y += v.y; s.z += v.z; s.w += v.w;
    }
    *(float4*)(Lg + i) = s;
}

// softmax rows of 512, packed hi/lo bf16 in place (k3 needs both planes)
__global__ __launch_bounds__(256) void k_softmax_pack512(float* __restrict__ Lg) {
    __shared__ float buf[512];
    __shared__ float red[256];
    const int tid = threadIdx.x;
    float* row = Lg + (size_t)blockIdx.x * 512;
    float2 v = *(const float2*)(row + tid * 2);
    buf[tid * 2] = v.x;
    buf[tid * 2 + 1] = v.y;
    red[tid] = fmaxf(v.x, v.y);
    __syncthreads();
    for (int s = 128; s > 0; s >>= 1) {
        if (tid < s) red[tid] = fmaxf(red[tid], red[tid + s]);
        __syncthreads();
    }
    float m = red[0];
    __syncthreads();
    float e0 = expf(buf[tid * 2] - m), e1 = expf(buf[tid * 2 + 1] - m);
    buf[tid * 2] = e0;
    buf[tid * 2 + 1] = e1;
    red[tid] = e0 + e1;
    __syncthreads();
    for (int s = 128; s > 0; s >>= 1) {
        if (tid < s) red[tid] += red[tid + s];
        __syncthreads();
    }
    float inv = 1.0f / red[0];
    u16* u = (u16*)row;
    u16 h0, l0, h1, l1;
    split_bf16(buf[tid * 2] * inv, h0, l0);
    split_bf16(buf[tid * 2 + 1] * inv, h1, l1);
    __syncthreads();
    u[tid * 2] = h0;
    u[tid * 2 + 1] = h1;
    u[512 + tid * 2] = l0;
    u[512 + tid * 2 + 1] = l1;
}

// ---------------------------------------------------------------------------
// k3 MFMA (3-term): Y[c][n] = sum_d A[c][d]*pq[d][n] + x[c][n]
// ---------------------------------------------------------------------------
__global__ __launch_bounds__(256, 2) void k3_mfma(const u16* __restrict__ Lu,
                                                  const u16* __restrict__ XT1hi,
                                                  const u16* __restrict__ XT1lo,
                                                  const float* __restrict__ X,
                                                  u16* __restrict__ Yhi,
                                                  u16* __restrict__ Ylo) {
    __shared__ __align__(16) char smem[32768];
    char* Ahi = smem;
    char* Alo = smem + 8192;
    char* Bhi = smem + 16384;
    char* Blo = smem + 24576;
    const int b = blockIdx.z;
    const u16* Au = Lu + (size_t)b * CH * 1024;
    const size_t boff = (size_t)b * CH * NSP;
    const float* Xb = X + boff;
    const int tid = threadIdx.x, lane = tid & 63, w = tid >> 6;
    const int wr = w >> 1, wc = w & 1;
    const int c0 = blockIdx.y * 128, n0 = blockIdx.x * 128;
    const int rl = lane >> 2;
    const int cb = (lane & 3) * 8;
    f32x4 acc[4][4];
#pragma unroll
    for (int i = 0; i < 4; i++)
#pragma unroll
        for (int j = 0; j < 4; j++) acc[i][j] = (f32x4){0.f, 0.f, 0.f, 0.f};

    for (int k0 = 0; k0 < CH; k0 += 32) {
#pragma unroll
        for (int s = 0; s < 2; s++) {
            int idx = w * 2 + s;
            int row = 16 * idx + rl;
            gload16(Au + (size_t)(c0 + row) * 1024 + k0 + cb, Ahi + idx * 1024);
            gload16(Au + (size_t)(c0 + row) * 1024 + 512 + k0 + cb, Alo + idx * 1024);
            gload16(XT1hi + boff + (size_t)(n0 + row) * CH + k0 + cb, Bhi + idx * 1024);
            gload16(XT1lo + boff + (size_t)(n0 + row) * CH + k0 + cb, Blo + idx * 1024);
        }
        __syncthreads();
        bfrag8 ah[4], al[4], bh[4], bl[4];
        const int q16 = (lane >> 4) * 16;
        const int l15 = (lane & 15);
#pragma unroll
        for (int i = 0; i < 4; i++) {
            int offa = (wr * 64 + i * 16 + l15) * 64 + q16;
            ah[i] = *(const bfrag8*)(Ahi + offa);
            al[i] = *(const bfrag8*)(Alo + offa);
            int offb = (wc * 64 + i * 16 + l15) * 64 + q16;
            bh[i] = *(const bfrag8*)(Bhi + offb);
            bl[i] = *(const bfrag8*)(Blo + offb);
        }
#pragma unroll
        for (int i = 0; i < 4; i++)
#pragma unroll
            for (int j = 0; j < 4; j++) {
                acc[i][j] = __builtin_amdgcn_mfma_f32_16x16x32_bf16(ah[i], bh[j], acc[i][j], 0, 0, 0);
                acc[i][j] = __builtin_amdgcn_mfma_f32_16x16x32_bf16(ah[i], bl[j], acc[i][j], 0, 0, 0);
                acc[i][j] = __builtin_amdgcn_mfma_f32_16x16x32_bf16(al[i], bh[j], acc[i][j], 0, 0, 0);
            }
        __syncthreads();
    }
    u16* Yhb = Yhi + boff;
    u16* Ylb = Ylo + boff;
    const int col = lane & 15, qr = (lane >> 4) * 4;
#pragma unroll
    for (int i = 0; i < 4; i++)
#pragma unroll
        for (int j = 0; j < 4; j++)
#pragma unroll
            for (int r = 0; r < 4; r++) {
                int c = c0 + wr * 64 + 16 * i + qr + r;
                int n = n0 + wc * 64 + 16 * j + col;
                float v = acc[i][j][r] + Xb[(size_t)c * NSP + n];
                u16 h, l;
                split_bf16(v, h, l);
                Yhb[(size_t)c * NSP + n] = h;
                Ylb[(size_t)c * NSP + n] = l;
            }
}

// ---------------------------------------------------------------------------
// k4 MFMA symmetric (3-term): triangular grid, mirror via padded-LDS transpose
// ---------------------------------------------------------------------------
__global__ __launch_bounds__(256, 2) void k4_mfma(const u16* __restrict__ YThi,
                                                  const u16* __restrict__ YTlo,
                                                  float* __restrict__ S) {
    __shared__ __align__(16) char smem[34816];
    char* Ahi = smem;
    char* Alo = smem + 8192;
    char* Bhi = smem + 16384;
    char* Blo = smem + 24576;
    const int tid = threadIdx.x, lane = tid & 63, w = tid >> 6;
    const int wr = w >> 1, wc = w & 1;
    int idx = blockIdx.x;
    int bi = (int)((sqrtf(8.f * (float)idx + 1.f) - 1.f) * 0.5f);
    while ((bi + 1) * (bi + 2) / 2 <= idx) bi++;
    while (bi * (bi + 1) / 2 > idx) bi--;
    int bj = idx - bi * (bi + 1) / 2;
    const int n0 = bi * 128, m0 = bj * 128;
    const bool diag = (bi == bj);
    const int rl = lane >> 2;
    const int cb = (lane & 3) * 8;
    f32x4 acc[4][4];
#pragma unroll
    for (int i = 0; i < 4; i++)
#pragma unroll
        for (int j = 0; j < 4; j++) acc[i][j] = (f32x4){0.f, 0.f, 0.f, 0.f};

    for (int k0 = 0; k0 < CH; k0 += 32) {
#pragma unroll
        for (int s = 0; s < 2; s++) {
            int i2 = w * 2 + s;
            int row = 16 * i2 + rl;
            gload16(YThi + (size_t)(n0 + row) * CH + k0 + cb, Ahi + i2 * 1024);
            gload16(YTlo + (size_t)(n0 + row) * CH + k0 + cb, Alo + i2 * 1024);
            gload16(YThi + (size_t)(m0 + row) * CH + k0 + cb, Bhi + i2 * 1024);
            gload16(YTlo + (size_t)(m0 + row) * CH + k0 + cb, Blo + i2 * 1024);
        }
        __syncthreads();
        bfrag8 ah[4], al[4], bh[4], bl[4];
        const int q16 = (lane >> 4) * 16;
        const int l15 = (lane & 15);
#pragma unroll
        for (int i = 0; i < 4; i++) {
            int offa = (wr * 64 + i * 16 + l15) * 64 + q16;
            ah[i] = *(const bfrag8*)(Ahi + offa);
            al[i] = *(const bfrag8*)(Alo + offa);
            int offb = (wc * 64 + i * 16 + l15) * 64 + q16;
            bh[i] = *(const bfrag8*)(Bhi + offb);
            bl[i] = *(const bfrag8*)(Blo + offb);
        }
#pragma unroll
        for (int i = 0; i < 4; i++)
#pragma unroll
            for (int j = 0; j < 4; j++) {
                acc[i][j] = __builtin_amdgcn_mfma_f32_16x16x32_bf16(ah[i], bh[j], acc[i][j], 0, 0, 0);
                acc[i][j] = __builtin_amdgcn_mfma_f32_16x16x32_bf16(ah[i], bl[j], acc[i][j], 0, 0, 0);
                acc[i][j] = __builtin_amdgcn_mfma_f32_16x16x32_bf16(al[i], bh[j], acc[i][j], 0, 0, 0);
            }
        __syncthreads();
    }
    const int col = lane & 15, qr = (lane >> 4) * 4;
#pragma unroll
    for (int i = 0; i < 4; i++)
#pragma unroll
        for (int j = 0; j < 4; j++)
#pragma unroll
            for (int r = 0; r < 4; r++)
                S[(size_t)(n0 + wr * 64 + 16 * i + qr + r) * NSP + m0 + wc * 64 + 16 * j + col] =
                    acc[i][j][r];
    if (!diag) {
        float* Tbase = (float*)smem;
#pragma unroll
        for (int round = 0; round < 2; round++) {
            if (wr == round) {
                float* T = Tbase + wc * (64 * 68);
#pragma unroll
                for (int i = 0; i < 4; i++)
#pragma unroll
                    for (int j = 0; j < 4; j++)
#pragma unroll
                        for (int r = 0; r < 4; r++)
                            T[(16 * j + col) * 68 + 16 * i + qr + r] = acc[i][j][r];
            }
            __syncthreads();
            if (wr == round) {
                float* T = Tbase + wc * (64 * 68);
                const int rq = (lane & 15) * 4;
#pragma unroll
                for (int rep = 0; rep < 16; rep++) {
                    int cq = rep * 4 + (lane >> 4);
                    float4 v = *(const float4*)(T + cq * 68 + rq);
                    *(float4*)(S + (size_t)(m0 + wc * 64 + cq) * NSP + n0 + wr * 64 + rq) = v;
                }
            }
            __syncthreads();
        }
    }
}

// softmax rows of 4096; writes ONLY the hi bf16 plane (k6 is 2-term in P)
__global__ __launch_bounds__(256) void k_softmax_pack(float* __restrict__ S) {
    __shared__ float buf[4096];
    __shared__ float red[256];
    const int tid = threadIdx.x;
    float* row = S + (size_t)blockIdx.x * NSP;
    float m = -INFINITY;
#pragma unroll
    for (int it = 0; it < 4; it++) {
        int i = (tid + it * 256) * 4;
        float4 v = *(const float4*)(row + i);
        buf[i] = v.x; buf[i + 1] = v.y; buf[i + 2] = v.z; buf[i + 3] = v.w;
        m = fmaxf(m, fmaxf(fmaxf(v.x, v.y), fmaxf(v.z, v.w)));
    }
    red[tid] = m;
    __syncthreads();
    for (int s = 128; s > 0; s >>= 1) {
        if (tid < s) red[tid] = fmaxf(red[tid], red[tid + s]);
        __syncthreads();
    }
    m = red[0];
    __syncthreads();
    float sum = 0.f;
#pragma unroll
    for (int it = 0; it < 4; it++) {
        int i = (tid + it * 256) * 4;
        float e0 = expf(buf[i] - m), e1 = expf(buf[i + 1] - m);
        float e2 = expf(buf[i + 2] - m), e3 = expf(buf[i + 3] - m);
        buf[i] = e0; buf[i + 1] = e1; buf[i + 2] = e2; buf[i + 3] = e3;
        sum += e0 + e1 + e2 + e3;
    }
    red[tid] = sum;
    __syncthreads();
    for (int s = 128; s > 0; s >>= 1) {
        if (tid < s) red[tid] += red[tid + s];
        __syncthreads();
    }
    float inv = 1.0f / red[0];
    u16* u = (u16*)row;
#pragma unroll
    for (int it = 0; it < 4; it++) {
        int i = (tid + it * 256) * 4;
        ushort4 hv;
        hv.x = (u16)(__float_as_uint(buf[i] * inv) >> 16);
        hv.y = (u16)(__float_as_uint(buf[i + 1] * inv) >> 16);
        hv.z = (u16)(__float_as_uint(buf[i + 2] * inv) >> 16);
        hv.w = (u16)(__float_as_uint(buf[i + 3] * inv) >> 16);
        *(ushort4*)(u + i) = hv;
    }
}

// ---------------------------------------------------------------------------
// k6 MFMA 2-term: out[c][m] = sum_n (yh+yl)[c][n] * Ph[m][n]; split-K=4.
// Dropping y*Pl costs <= max|y|*2^-9 ~ 0.01 abs — well under threshold.
// ---------------------------------------------------------------------------
__global__ __launch_bounds__(256, 2) void k6_mfma(const u16* __restrict__ Yhi,
                                                  const u16* __restrict__ Ylo,
                                                  const u16* __restrict__ Ppk,
                                                  float* __restrict__ Pp) {
    __shared__ __align__(16) char smem[24576];
    char* Ahi = smem;
    char* Alo = smem + 8192;
    char* Bhi = smem + 16384;
    const int tid = threadIdx.x, lane = tid & 63, w = tid >> 6;
    const int wr = w >> 1, wc = w & 1;
    const int m0 = blockIdx.x * 128, c0 = blockIdx.y * 128, z = blockIdx.z;
    const int kb = z * 1024;
    const int rl = lane >> 2;
    const int cb = (lane & 3) * 8;
    f32x4 acc[4][4];
#pragma unroll
    for (int i = 0; i < 4; i++)
#pragma unroll
        for (int j = 0; j < 4; j++) acc[i][j] = (f32x4){0.f, 0.f, 0.f, 0.f};

    for (int k0 = 0; k0 < 1024; k0 += 32) {
        const int kk = kb + k0;
#pragma unroll
        for (int s = 0; s < 2; s++) {
            int idx = w * 2 + s;
            int row = 16 * idx + rl;
            gload16(Yhi + (size_t)(c0 + row) * NSP + kk + cb, Ahi + idx * 1024);
            gload16(Ylo + (size_t)(c0 + row) * NSP + kk + cb, Alo + idx * 1024);
            gload16(Ppk + (size_t)(m0 + row) * 8192 + kk + cb, Bhi + idx * 1024);
        }
        __syncthreads();
        bfrag8 ah[4], al[4], bh[4];
        const int q16 = (lane >> 4) * 16;
        const int l15 = (lane & 15);
#pragma unroll
        for (int i = 0; i < 4; i++) {
            int offa = (wr * 64 + i * 16 + l15) * 64 + q16;
            ah[i] = *(const bfrag8*)(Ahi + offa);
            al[i] = *(const bfrag8*)(Alo + offa);
            int offb = (wc * 64 + i * 16 + l15) * 64 + q16;
            bh[i] = *(const bfrag8*)(Bhi + offb);
        }
#pragma unroll
        for (int i = 0; i < 4; i++)
#pragma unroll
            for (int j = 0; j < 4; j++) {
                acc[i][j] = __builtin_amdgcn_mfma_f32_16x16x32_bf16(ah[i], bh[j], acc[i][j], 0, 0, 0);
                acc[i][j] = __builtin_amdgcn_mfma_f32_16x16x32_bf16(al[i], bh[j], acc[i][j], 0, 0, 0);
            }
        __syncthreads();
    }
    float* out = Pp + (size_t)z * CH * NSP;
    const int col = lane & 15, qr = (lane >> 4) * 4;
#pragma unroll
    for (int i = 0; i < 4; i++)
#pragma unroll
        for (int j = 0; j < 4; j++)
#pragma unroll
            for (int r = 0; r < 4; r++)
                out[(size_t)(c0 + wr * 64 + 16 * i + qr + r) * NSP + m0 + wc * 64 + 16 * j + col] =
                    acc[i][j][r];
}

__global__ __launch_bounds__(256) void k_combine(const float* __restrict__ Pp,
                                                 const u16* __restrict__ Yhi,
                                                 const u16* __restrict__ Ylo,
                                                 float* __restrict__ outb) {
    const size_t CN = (size_t)CH * NSP;
    size_t i = ((size_t)blockIdx.x * 256 + threadIdx.x) * 4;
    float4 a = *(const float4*)(Pp + i);
    float4 b = *(const float4*)(Pp + CN + i);
    float4 c = *(const float4*)(Pp + 2 * CN + i);
    float4 d = *(const float4*)(Pp + 3 * CN + i);
    ushort4 h = *(const ushort4*)(Yhi + i);
    ushort4 l = *(const ushort4*)(Ylo + i);
    float4 o;
    o.x = a.x + b.x + c.x + d.x + join_bf16(h.x, l.x);
    o.y = a.y + b.y + c.y + d.y + join_bf16(h.y, l.y);
    o.z = a.z + b.z + c.z + d.z + join_bf16(h.z, l.z);
    o.w = a.w + b.w + c.w + d.w + join_bf16(h.w, l.w);
    *(float4*)(outb + i) = o;
}

extern "C" void kernel_launch(void* const* d_in, const int* in_sizes, int n_in,
                              void* d_out, int out_size, void* d_ws, size_t ws_size,
                              hipStream_t stream) {
    const float* x = (const float*)d_in[0];
    float* out = (float*)d_out;

    // workspace layout (16MB units), aliasing:
    //   [0..6): XHi|XLo|XT2hi|XT2lo|XT1hi|XT1lo (dead after k3); S aliases [0..4)
    //   [6..10): Yhi|Ylo|YThi|YTlo (live to end)
    //   Lg at 10*SZ16 (4MB); Pp after (32MB; also k1 split-K partials)
    char* p = (char*)d_ws;
    const size_t SZ16 = (size_t)BATCH * CH * NSP * 2;  // 16 MB
    u16* XHi = (u16*)p;
    u16* XLo = (u16*)(p + SZ16);
    u16* XT2hi = (u16*)(p + 2 * SZ16);
    u16* XT2lo = (u16*)(p + 3 * SZ16);
    u16* XT1hi = (u16*)(p + 4 * SZ16);
    u16* XT1lo = (u16*)(p + 5 * SZ16);
    float* S = (float*)p;
    u16* Yhi = (u16*)(p + 6 * SZ16);
    u16* Ylo = (u16*)(p + 7 * SZ16);
    u16* YThi = (u16*)(p + 8 * SZ16);
    u16* YTlo = (u16*)(p + 9 * SZ16);
    float* Lg = (float*)(p + 10 * SZ16);
    float* Pp = (float*)(p + 10 * SZ16 + (size_t)BATCH * CH * CH * 4);

    // Stage 1: channel attention
    k_prep_cn<<<dim3(NSP / 64, CH / 64, BATCH), 256, 0, stream>>>(x, XHi, XLo, XT1hi, XT1lo);
    k_prep_nc<<<dim3(NSP / 64, CH / 64, BATCH), 256, 0, stream>>>(x, XT2hi, XT2lo);
    k1_mfma<<<dim3(512), 256, 0, stream>>>(XHi, XLo, XT2hi, XT2lo, Pp);
    k_combine8<<<dim3((BATCH * CH * CH) / (4 * 256)), 256, 0, stream>>>(Pp, Lg);
    k_softmax_pack512<<<dim3(BATCH * CH), 256, 0, stream>>>(Lg);
    k3_mfma<<<dim3(NSP / 128, CH / 128, BATCH), 256, 0, stream>>>((const u16*)Lg, XT1hi, XT1lo, x,
                                                                  Yhi, Ylo);
    k_transpose_split<<<dim3(CH / 64, NSP / 64, BATCH), 256, 0, stream>>>(Yhi, Ylo, YThi, YTlo,
                                                                          CH, NSP);

    // Stage 2: positional attention per batch
    const int TRI = (NSP / 128) * (NSP / 128 + 1) / 2;  // 528
    for (int b = 0; b < BATCH; b++) {
        const u16* YThib = YThi + (size_t)b * NSP * CH;
        const u16* YTlob = YTlo + (size_t)b * NSP * CH;
        const u16* Yhib = Yhi + (size_t)b * CH * NSP;
        const u16* Ylob = Ylo + (size_t)b * CH * NSP;
        k4_mfma<<<dim3(TRI), 256, 0, stream>>>(YThib, YTlob, S);
        k_softmax_pack<<<dim3(NSP), 256, 0, stream>>>(S);
        k6_mfma<<<dim3(NSP / 128, CH / 128, 4), 256, 0, stream>>>(Yhib, Ylob, (const u16*)S, Pp);
        k_combine<<<dim3((CH * NSP) / (4 * 256)), 256, 0, stream>>>(Pp, Yhib, Ylob,
                                                                    out + (size_t)b * CH * NSP);
    }
}

// Round 7
// 554.107 us; speedup vs baseline: 5.2066x; 1.0863x over previous
//
#include <hip/hip_runtime.h>

#define BATCH 4
#define CH 512
#define NSP 4096   // 64*64 spatial

typedef __attribute__((ext_vector_type(8))) short bfrag8;  // 8 bf16 (4 VGPRs)
typedef __attribute__((ext_vector_type(4))) float f32x4;
typedef unsigned short u16;

#define AS1 __attribute__((address_space(1)))
#define AS3 __attribute__((address_space(3)))
__device__ __forceinline__ void gload16(const void* g, void* l) {
    __builtin_amdgcn_global_load_lds((const AS1 void*)g, (AS3 void*)l, 16, 0, 0);
}

__device__ __forceinline__ void split_bf16(float y, u16& h, u16& l) {
    unsigned int u = __float_as_uint(y);
    h = (u16)(u >> 16);
    float r = y - __uint_as_float(((unsigned int)h) << 16);
    l = (u16)(__float_as_uint(r) >> 16);
}
__device__ __forceinline__ float join_bf16(u16 h, u16 l) {
    return __uint_as_float(((unsigned int)h) << 16) + __uint_as_float(((unsigned int)l) << 16);
}

// ---------------------------------------------------------------------------
// prep 1: x [C][N] view -> XHi/XLo (same layout) + XT1 [n][c] (transpose)
// ---------------------------------------------------------------------------
__global__ __launch_bounds__(256) void k_prep_cn(const float* __restrict__ X,
                                                 u16* __restrict__ XHi,
                                                 u16* __restrict__ XLo,
                                                 u16* __restrict__ XT1hi,
                                                 u16* __restrict__ XT1lo) {
    __shared__ unsigned int t[64][65];
    const size_t boff = (size_t)blockIdx.z * CH * NSP;
    const int c0 = blockIdx.y * 64, n0 = blockIdx.x * 64;
    const int r = threadIdx.x >> 4, col4 = (threadIdx.x & 15) * 4;
#pragma unroll
    for (int it = 0; it < 4; it++) {
        int rl = r + it * 16;
        float4 v = *(const float4*)(X + boff + (size_t)(c0 + rl) * NSP + n0 + col4);
        ushort4 h, l;
        split_bf16(v.x, h.x, l.x);
        split_bf16(v.y, h.y, l.y);
        split_bf16(v.z, h.z, l.z);
        split_bf16(v.w, h.w, l.w);
        *(ushort4*)(XHi + boff + (size_t)(c0 + rl) * NSP + n0 + col4) = h;
        *(ushort4*)(XLo + boff + (size_t)(c0 + rl) * NSP + n0 + col4) = l;
        t[rl][col4 + 0] = ((unsigned int)h.x << 16) | l.x;
        t[rl][col4 + 1] = ((unsigned int)h.y << 16) | l.y;
        t[rl][col4 + 2] = ((unsigned int)h.z << 16) | l.z;
        t[rl][col4 + 3] = ((unsigned int)h.w << 16) | l.w;
    }
    __syncthreads();
#pragma unroll
    for (int it = 0; it < 4; it++) {
        int cl = r + it * 16;
        unsigned int p0 = t[col4 + 0][cl];
        unsigned int p1 = t[col4 + 1][cl];
        unsigned int p2 = t[col4 + 2][cl];
        unsigned int p3 = t[col4 + 3][cl];
        ushort4 hv, lv;
        hv.x = p0 >> 16; hv.y = p1 >> 16; hv.z = p2 >> 16; hv.w = p3 >> 16;
        lv.x = p0 & 0xffff; lv.y = p1 & 0xffff; lv.z = p2 & 0xffff; lv.w = p3 & 0xffff;
        *(ushort4*)(XT1hi + boff + (size_t)(n0 + cl) * CH + c0 + col4) = hv;
        *(ushort4*)(XT1lo + boff + (size_t)(n0 + cl) * CH + c0 + col4) = lv;
    }
}

// prep 2: x [N][C] view -> XT2 [d][n] (transpose)
__global__ __launch_bounds__(256) void k_prep_nc(const float* __restrict__ X,
                                                 u16* __restrict__ XT2hi,
                                                 u16* __restrict__ XT2lo) {
    __shared__ unsigned int t[64][65];
    const size_t boff = (size_t)blockIdx.z * CH * NSP;
    const int n0 = blockIdx.x * 64, d0 = blockIdx.y * 64;
    const int r = threadIdx.x >> 4, col4 = (threadIdx.x & 15) * 4;
#pragma unroll
    for (int it = 0; it < 4; it++) {
        int rl = r + it * 16;
        float4 v = *(const float4*)(X + boff + (size_t)(n0 + rl) * CH + d0 + col4);
        ushort4 h, l;
        split_bf16(v.x, h.x, l.x);
        split_bf16(v.y, h.y, l.y);
        split_bf16(v.z, h.z, l.z);
        split_bf16(v.w, h.w, l.w);
        t[rl][col4 + 0] = ((unsigned int)h.x << 16) | l.x;
        t[rl][col4 + 1] = ((unsigned int)h.y << 16) | l.y;
        t[rl][col4 + 2] = ((unsigned int)h.z << 16) | l.z;
        t[rl][col4 + 3] = ((unsigned int)h.w << 16) | l.w;
    }
    __syncthreads();
#pragma unroll
    for (int it = 0; it < 4; it++) {
        int cl = r + it * 16;
        unsigned int p0 = t[col4 + 0][cl];
        unsigned int p1 = t[col4 + 1][cl];
        unsigned int p2 = t[col4 + 2][cl];
        unsigned int p3 = t[col4 + 3][cl];
        ushort4 hv, lv;
        hv.x = p0 >> 16; hv.y = p1 >> 16; hv.z = p2 >> 16; hv.w = p3 >> 16;
        lv.x = p0 & 0xffff; lv.y = p1 & 0xffff; lv.z = p2 & 0xffff; lv.w = p3 & 0xffff;
        *(ushort4*)(XT2hi + boff + (size_t)(d0 + cl) * NSP + n0 + col4) = hv;
        *(ushort4*)(XT2lo + boff + (size_t)(d0 + cl) * NSP + n0 + col4) = lv;
    }
}

// transpose a split pair: src [R][Cc] -> dst [Cc][R]
__global__ __launch_bounds__(256) void k_transpose_split(const u16* __restrict__ Hs,
                                                         const u16* __restrict__ Ls,
                                                         u16* __restrict__ Hd,
                                                         u16* __restrict__ Ld,
                                                         int R, int Cc) {
    __shared__ unsigned int t[64][65];
    const size_t off = (size_t)blockIdx.z * R * Cc;
    const int r0 = blockIdx.x * 64, c0 = blockIdx.y * 64;
    const int r = threadIdx.x >> 4, col4 = (threadIdx.x & 15) * 4;
#pragma unroll
    for (int it = 0; it < 4; it++) {
        int rl = r + it * 16;
        ushort4 h = *(const ushort4*)(Hs + off + (size_t)(r0 + rl) * Cc + c0 + col4);
        ushort4 l = *(const ushort4*)(Ls + off + (size_t)(r0 + rl) * Cc + c0 + col4);
        t[rl][col4 + 0] = ((unsigned int)h.x << 16) | l.x;
        t[rl][col4 + 1] = ((unsigned int)h.y << 16) | l.y;
        t[rl][col4 + 2] = ((unsigned int)h.z << 16) | l.z;
        t[rl][col4 + 3] = ((unsigned int)h.w << 16) | l.w;
    }
    __syncthreads();
#pragma unroll
    for (int it = 0; it < 4; it++) {
        int cl = r + it * 16;
        unsigned int p0 = t[col4 + 0][cl];
        unsigned int p1 = t[col4 + 1][cl];
        unsigned int p2 = t[col4 + 2][cl];
        unsigned int p3 = t[col4 + 3][cl];
        ushort4 hv, lv;
        hv.x = p0 >> 16; hv.y = p1 >> 16; hv.z = p2 >> 16; hv.w = p3 >> 16;
        lv.x = p0 & 0xffff; lv.y = p1 & 0xffff; lv.z = p2 & 0xffff; lv.w = p3 & 0xffff;
        *(ushort4*)(Hd + off + (size_t)(c0 + cl) * R + r0 + col4) = hv;
        *(ushort4*)(Ld + off + (size_t)(c0 + cl) * R + r0 + col4) = lv;
    }
}

// ---------------------------------------------------------------------------
// k1 MFMA split-K=8 with XCD swizzle; partials -> Pk (aliases Y region)
// ---------------------------------------------------------------------------
__global__ __launch_bounds__(256, 2) void k1_mfma(const u16* __restrict__ XHi,
                                                  const u16* __restrict__ XLo,
                                                  const u16* __restrict__ XT2hi,
                                                  const u16* __restrict__ XT2lo,
                                                  float* __restrict__ Pk) {
    __shared__ __align__(16) char smem[32768];
    char* Ahi = smem;
    char* Alo = smem + 8192;
    char* Bhi = smem + 16384;
    char* Blo = smem + 24576;
    const int bid = blockIdx.x;
    const int xcd = bid & 7;
    const int i1 = bid >> 3;
    const int group = xcd * 4 + (i1 >> 4);
    const int b = group >> 3, kz = group & 7;
    const int tile = i1 & 15;
    const int c0 = (tile >> 2) * 128, d0 = (tile & 3) * 128;
    const size_t boff = (size_t)b * CH * NSP;
    const int tid = threadIdx.x, lane = tid & 63, w = tid >> 6;
    const int wr = w >> 1, wc = w & 1;
    const int rl = lane >> 2;
    const int cb = (lane & 3) * 8;
    f32x4 acc[4][4];
#pragma unroll
    for (int i = 0; i < 4; i++)
#pragma unroll
        for (int j = 0; j < 4; j++) acc[i][j] = (f32x4){0.f, 0.f, 0.f, 0.f};

    const int kbeg = kz * 512, kend = kbeg + 512;
    for (int k0 = kbeg; k0 < kend; k0 += 32) {
#pragma unroll
        for (int s = 0; s < 2; s++) {
            int idx = w * 2 + s;
            int row = 16 * idx + rl;
            gload16(XHi + boff + (size_t)(c0 + row) * NSP + k0 + cb, Ahi + idx * 1024);
            gload16(XLo + boff + (size_t)(c0 + row) * NSP + k0 + cb, Alo + idx * 1024);
            gload16(XT2hi + boff + (size_t)(d0 + row) * NSP + k0 + cb, Bhi + idx * 1024);
            gload16(XT2lo + boff + (size_t)(d0 + row) * NSP + k0 + cb, Blo + idx * 1024);
        }
        __syncthreads();
        bfrag8 ah[4], al[4], bh[4], bl[4];
        const int q16 = (lane >> 4) * 16;
        const int l15 = (lane & 15);
#pragma unroll
        for (int i = 0; i < 4; i++) {
            int offa = (wr * 64 + i * 16 + l15) * 64 + q16;
            ah[i] = *(const bfrag8*)(Ahi + offa);
            al[i] = *(const bfrag8*)(Alo + offa);
            int offb = (wc * 64 + i * 16 + l15) * 64 + q16;
            bh[i] = *(const bfrag8*)(Bhi + offb);
            bl[i] = *(const bfrag8*)(Blo + offb);
        }
#pragma unroll
        for (int i = 0; i < 4; i++)
#pragma unroll
            for (int j = 0; j < 4; j++) {
                acc[i][j] = __builtin_amdgcn_mfma_f32_16x16x32_bf16(ah[i], bh[j], acc[i][j], 0, 0, 0);
                acc[i][j] = __builtin_amdgcn_mfma_f32_16x16x32_bf16(ah[i], bl[j], acc[i][j], 0, 0, 0);
                acc[i][j] = __builtin_amdgcn_mfma_f32_16x16x32_bf16(al[i], bh[j], acc[i][j], 0, 0, 0);
            }
        __syncthreads();
    }
    float* Lb = Pk + (size_t)kz * BATCH * CH * CH + (size_t)b * CH * CH;
    const int col = lane & 15, qr = (lane >> 4) * 4;
#pragma unroll
    for (int i = 0; i < 4; i++)
#pragma unroll
        for (int j = 0; j < 4; j++)
#pragma unroll
            for (int r = 0; r < 4; r++)
                Lb[(size_t)(c0 + wr * 64 + 16 * i + qr + r) * CH + d0 + wc * 64 + 16 * j + col] =
                    acc[i][j][r];
}

__global__ __launch_bounds__(256) void k_combine8(const float* __restrict__ Pk,
                                                  float* __restrict__ Lg) {
    const size_t MM = (size_t)BATCH * CH * CH;
    size_t i = ((size_t)blockIdx.x * 256 + threadIdx.x) * 4;
    float4 s = *(const float4*)(Pk + i);
#pragma unroll
    for (int z = 1; z < 8; z++) {
        float4 v = *(const float4*)(Pk + z * MM + i);
        s.x += v.x; s.y += v.y; s.z += v.z; s.w += v.w;
    }
    *(float4*)(Lg + i) = s;
}

// softmax rows of 512 -> packed hi/lo bf16 in place
__global__ __launch_bounds__(256) void k_softmax_pack512(float* __restrict__ Lg) {
    __shared__ float buf[512];
    __shared__ float red[256];
    const int tid = threadIdx.x;
    float* row = Lg + (size_t)blockIdx.x * 512;
    float2 v = *(const float2*)(row + tid * 2);
    buf[tid * 2] = v.x;
    buf[tid * 2 + 1] = v.y;
    red[tid] = fmaxf(v.x, v.y);
    __syncthreads();
    for (int s = 128; s > 0; s >>= 1) {
        if (tid < s) red[tid] = fmaxf(red[tid], red[tid + s]);
        __syncthreads();
    }
    float m = red[0];
    __syncthreads();
    float e0 = __expf(buf[tid * 2] - m), e1 = __expf(buf[tid * 2 + 1] - m);
    buf[tid * 2] = e0;
    buf[tid * 2 + 1] = e1;
    red[tid] = e0 + e1;
    __syncthreads();
    for (int s = 128; s > 0; s >>= 1) {
        if (tid < s) red[tid] += red[tid + s];
        __syncthreads();
    }
    float inv = 1.0f / red[0];
    u16* u = (u16*)row;
    u16 h0, l0, h1, l1;
    split_bf16(buf[tid * 2] * inv, h0, l0);
    split_bf16(buf[tid * 2 + 1] * inv, h1, l1);
    __syncthreads();
    u[tid * 2] = h0;
    u[tid * 2 + 1] = h1;
    u[512 + tid * 2] = l0;
    u[512 + tid * 2 + 1] = l1;
}

// k3 MFMA (3-term): Y = A*pq + x, split output
__global__ __launch_bounds__(256, 2) void k3_mfma(const u16* __restrict__ Lu,
                                                  const u16* __restrict__ XT1hi,
                                                  const u16* __restrict__ XT1lo,
                                                  const float* __restrict__ X,
                                                  u16* __restrict__ Yhi,
                                                  u16* __restrict__ Ylo) {
    __shared__ __align__(16) char smem[32768];
    char* Ahi = smem;
    char* Alo = smem + 8192;
    char* Bhi = smem + 16384;
    char* Blo = smem + 24576;
    const int b = blockIdx.z;
    const u16* Au = Lu + (size_t)b * CH * 1024;
    const size_t boff = (size_t)b * CH * NSP;
    const float* Xb = X + boff;
    const int tid = threadIdx.x, lane = tid & 63, w = tid >> 6;
    const int wr = w >> 1, wc = w & 1;
    const int c0 = blockIdx.y * 128, n0 = blockIdx.x * 128;
    const int rl = lane >> 2;
    const int cb = (lane & 3) * 8;
    f32x4 acc[4][4];
#pragma unroll
    for (int i = 0; i < 4; i++)
#pragma unroll
        for (int j = 0; j < 4; j++) acc[i][j] = (f32x4){0.f, 0.f, 0.f, 0.f};

    for (int k0 = 0; k0 < CH; k0 += 32) {
#pragma unroll
        for (int s = 0; s < 2; s++) {
            int idx = w * 2 + s;
            int row = 16 * idx + rl;
            gload16(Au + (size_t)(c0 + row) * 1024 + k0 + cb, Ahi + idx * 1024);
            gload16(Au + (size_t)(c0 + row) * 1024 + 512 + k0 + cb, Alo + idx * 1024);
            gload16(XT1hi + boff + (size_t)(n0 + row) * CH + k0 + cb, Bhi + idx * 1024);
            gload16(XT1lo + boff + (size_t)(n0 + row) * CH + k0 + cb, Blo + idx * 1024);
        }
        __syncthreads();
        bfrag8 ah[4], al[4], bh[4], bl[4];
        const int q16 = (lane >> 4) * 16;
        const int l15 = (lane & 15);
#pragma unroll
        for (int i = 0; i < 4; i++) {
            int offa = (wr * 64 + i * 16 + l15) * 64 + q16;
            ah[i] = *(const bfrag8*)(Ahi + offa);
            al[i] = *(const bfrag8*)(Alo + offa);
            int offb = (wc * 64 + i * 16 + l15) * 64 + q16;
            bh[i] = *(const bfrag8*)(Bhi + offb);
            bl[i] = *(const bfrag8*)(Blo + offb);
        }
#pragma unroll
        for (int i = 0; i < 4; i++)
#pragma unroll
            for (int j = 0; j < 4; j++) {
                acc[i][j] = __builtin_amdgcn_mfma_f32_16x16x32_bf16(ah[i], bh[j], acc[i][j], 0, 0, 0);
                acc[i][j] = __builtin_amdgcn_mfma_f32_16x16x32_bf16(ah[i], bl[j], acc[i][j], 0, 0, 0);
                acc[i][j] = __builtin_amdgcn_mfma_f32_16x16x32_bf16(al[i], bh[j], acc[i][j], 0, 0, 0);
            }
        __syncthreads();
    }
    u16* Yhb = Yhi + boff;
    u16* Ylb = Ylo + boff;
    const int col = lane & 15, qr = (lane >> 4) * 4;
#pragma unroll
    for (int i = 0; i < 4; i++)
#pragma unroll
        for (int j = 0; j < 4; j++)
#pragma unroll
            for (int r = 0; r < 4; r++) {
                int c = c0 + wr * 64 + 16 * i + qr + r;
                int n = n0 + wc * 64 + 16 * j + col;
                float v = acc[i][j][r] + Xb[(size_t)c * NSP + n];
                u16 h, l;
                split_bf16(v, h, l);
                Yhb[(size_t)c * NSP + n] = h;
                Ylb[(size_t)c * NSP + n] = l;
            }
}

// ---------------------------------------------------------------------------
// k4 MFMA symmetric (3-term), 2 batches per launch (blockIdx.y = rb).
// Triangular tiles + mirror write via padded-LDS transpose.
// ---------------------------------------------------------------------------
__global__ __launch_bounds__(256, 2) void k4_mfma(const u16* __restrict__ YThi0,
                                                  const u16* __restrict__ YTlo0,
                                                  float* __restrict__ S0) {
    __shared__ __align__(16) char smem[34816];
    char* Ahi = smem;
    char* Alo = smem + 8192;
    char* Bhi = smem + 16384;
    char* Blo = smem + 24576;
    const int tid = threadIdx.x, lane = tid & 63, w = tid >> 6;
    const int wr = w >> 1, wc = w & 1;
    const int rb = blockIdx.y;
    const u16* YThi = YThi0 + (size_t)rb * NSP * CH;
    const u16* YTlo = YTlo0 + (size_t)rb * NSP * CH;
    float* S = S0 + (size_t)rb * NSP * NSP;
    int idx = blockIdx.x;
    int bi = (int)((sqrtf(8.f * (float)idx + 1.f) - 1.f) * 0.5f);
    while ((bi + 1) * (bi + 2) / 2 <= idx) bi++;
    while (bi * (bi + 1) / 2 > idx) bi--;
    int bj = idx - bi * (bi + 1) / 2;
    const int n0 = bi * 128, m0 = bj * 128;
    const bool diag = (bi == bj);
    const int rl = lane >> 2;
    const int cb = (lane & 3) * 8;
    f32x4 acc[4][4];
#pragma unroll
    for (int i = 0; i < 4; i++)
#pragma unroll
        for (int j = 0; j < 4; j++) acc[i][j] = (f32x4){0.f, 0.f, 0.f, 0.f};

    for (int k0 = 0; k0 < CH; k0 += 32) {
#pragma unroll
        for (int s = 0; s < 2; s++) {
            int i2 = w * 2 + s;
            int row = 16 * i2 + rl;
            gload16(YThi + (size_t)(n0 + row) * CH + k0 + cb, Ahi + i2 * 1024);
            gload16(YTlo + (size_t)(n0 + row) * CH + k0 + cb, Alo + i2 * 1024);
            gload16(YThi + (size_t)(m0 + row) * CH + k0 + cb, Bhi + i2 * 1024);
            gload16(YTlo + (size_t)(m0 + row) * CH + k0 + cb, Blo + i2 * 1024);
        }
        __syncthreads();
        bfrag8 ah[4], al[4], bh[4], bl[4];
        const int q16 = (lane >> 4) * 16;
        const int l15 = (lane & 15);
#pragma unroll
        for (int i = 0; i < 4; i++) {
            int offa = (wr * 64 + i * 16 + l15) * 64 + q16;
            ah[i] = *(const bfrag8*)(Ahi + offa);
            al[i] = *(const bfrag8*)(Alo + offa);
            int offb = (wc * 64 + i * 16 + l15) * 64 + q16;
            bh[i] = *(const bfrag8*)(Bhi + offb);
            bl[i] = *(const bfrag8*)(Blo + offb);
        }
#pragma unroll
        for (int i = 0; i < 4; i++)
#pragma unroll
            for (int j = 0; j < 4; j++) {
                acc[i][j] = __builtin_amdgcn_mfma_f32_16x16x32_bf16(ah[i], bh[j], acc[i][j], 0, 0, 0);
                acc[i][j] = __builtin_amdgcn_mfma_f32_16x16x32_bf16(ah[i], bl[j], acc[i][j], 0, 0, 0);
                acc[i][j] = __builtin_amdgcn_mfma_f32_16x16x32_bf16(al[i], bh[j], acc[i][j], 0, 0, 0);
            }
        __syncthreads();
    }
    const int col = lane & 15, qr = (lane >> 4) * 4;
#pragma unroll
    for (int i = 0; i < 4; i++)
#pragma unroll
        for (int j = 0; j < 4; j++)
#pragma unroll
            for (int r = 0; r < 4; r++)
                S[(size_t)(n0 + wr * 64 + 16 * i + qr + r) * NSP + m0 + wc * 64 + 16 * j + col] =
                    acc[i][j][r];
    if (!diag) {
        float* Tbase = (float*)smem;
#pragma unroll
        for (int round = 0; round < 2; round++) {
            if (wr == round) {
                float* T = Tbase + wc * (64 * 68);
#pragma unroll
                for (int i = 0; i < 4; i++)
#pragma unroll
                    for (int j = 0; j < 4; j++)
#pragma unroll
                        for (int r = 0; r < 4; r++)
                            T[(16 * j + col) * 68 + 16 * i + qr + r] = acc[i][j][r];
            }
            __syncthreads();
            if (wr == round) {
                float* T = Tbase + wc * (64 * 68);
                const int rq = (lane & 15) * 4;
#pragma unroll
                for (int rep = 0; rep < 16; rep++) {
                    int cq = rep * 4 + (lane >> 4);
                    float4 v = *(const float4*)(T + cq * 68 + rq);
                    *(float4*)(S + (size_t)(m0 + wc * 64 + cq) * NSP + n0 + wr * 64 + rq) = v;
                }
            }
            __syncthreads();
        }
    }
}

// softmax rows of 4096 over contiguous S0|S1 (grid 8192); writes hi plane only
__global__ __launch_bounds__(256) void k_softmax_pack(float* __restrict__ S) {
    __shared__ float buf[4096];
    __shared__ float red[256];
    const int tid = threadIdx.x;
    float* row = S + (size_t)blockIdx.x * NSP;
    float m = -INFINITY;
#pragma unroll
    for (int it = 0; it < 4; it++) {
        int i = (tid + it * 256) * 4;
        float4 v = *(const float4*)(row + i);
        buf[i] = v.x; buf[i + 1] = v.y; buf[i + 2] = v.z; buf[i + 3] = v.w;
        m = fmaxf(m, fmaxf(fmaxf(v.x, v.y), fmaxf(v.z, v.w)));
    }
    red[tid] = m;
    __syncthreads();
    for (int s = 128; s > 0; s >>= 1) {
        if (tid < s) red[tid] = fmaxf(red[tid], red[tid + s]);
        __syncthreads();
    }
    m = red[0];
    __syncthreads();
    float sum = 0.f;
#pragma unroll
    for (int it = 0; it < 4; it++) {
        int i = (tid + it * 256) * 4;
        float e0 = __expf(buf[i] - m), e1 = __expf(buf[i + 1] - m);
        float e2 = __expf(buf[i + 2] - m), e3 = __expf(buf[i + 3] - m);
        buf[i] = e0; buf[i + 1] = e1; buf[i + 2] = e2; buf[i + 3] = e3;
        sum += e0 + e1 + e2 + e3;
    }
    red[tid] = sum;
    __syncthreads();
    for (int s = 128; s > 0; s >>= 1) {
        if (tid < s) red[tid] += red[tid + s];
        __syncthreads();
    }
    float inv = 1.0f / red[0];
    u16* u = (u16*)row;
#pragma unroll
    for (int it = 0; it < 4; it++) {
        int i = (tid + it * 256) * 4;
        ushort4 hv;
        hv.x = (u16)(__float_as_uint(buf[i] * inv) >> 16);
        hv.y = (u16)(__float_as_uint(buf[i + 1] * inv) >> 16);
        hv.z = (u16)(__float_as_uint(buf[i + 2] * inv) >> 16);
        hv.w = (u16)(__float_as_uint(buf[i + 3] * inv) >> 16);
        *(ushort4*)(u + i) = hv;
    }
}

__global__ __launch_bounds__(256) void k_zero(float* __restrict__ o) {
    size_t i = ((size_t)blockIdx.x * 256 + threadIdx.x) * 4;
    *(float4*)(o + i) = (float4){0.f, 0.f, 0.f, 0.f};
}

// ---------------------------------------------------------------------------
// k6 MFMA 1-term, split-K=2, 2 batches/launch (z = rb*2+kz), atomicAdd to out.
// kz==0 blocks also add the residual y = hi+lo.
// ---------------------------------------------------------------------------
__global__ __launch_bounds__(256, 2) void k6_mfma(const u16* __restrict__ Yhi0,
                                                  const u16* __restrict__ Ylo0,
                                                  const u16* __restrict__ Su,
                                                  float* __restrict__ Out0) {
    __shared__ __align__(16) char smem[16384];
    char* Ahi = smem;
    char* Bhi = smem + 8192;
    const int tid = threadIdx.x, lane = tid & 63, w = tid >> 6;
    const int wr = w >> 1, wc = w & 1;
    const int m0 = blockIdx.x * 128, c0 = blockIdx.y * 128;
    const int rb = blockIdx.z >> 1, kz = blockIdx.z & 1;
    const u16* Yhi = Yhi0 + (size_t)rb * CH * NSP;
    const u16* Ylo = Ylo0 + (size_t)rb * CH * NSP;
    const u16* Pu = Su + (size_t)rb * NSP * NSP * 2;  // S batch stride in u16 units
    float* Out = Out0 + (size_t)rb * CH * NSP;
    const int kb = kz * 2048;
    const int rl = lane >> 2;
    const int cb = (lane & 3) * 8;
    f32x4 acc[4][4];
#pragma unroll
    for (int i = 0; i < 4; i++)
#pragma unroll
        for (int j = 0; j < 4; j++) acc[i][j] = (f32x4){0.f, 0.f, 0.f, 0.f};

    for (int k0 = 0; k0 < 2048; k0 += 32) {
        const int kk = kb + k0;
#pragma unroll
        for (int s = 0; s < 2; s++) {
            int idx = w * 2 + s;
            int row = 16 * idx + rl;
            gload16(Yhi + (size_t)(c0 + row) * NSP + kk + cb, Ahi + idx * 1024);
            gload16(Pu + (size_t)(m0 + row) * 8192 + kk + cb, Bhi + idx * 1024);
        }
        __syncthreads();
        bfrag8 ah[4], bh[4];
        const int q16 = (lane >> 4) * 16;
        const int l15 = (lane & 15);
#pragma unroll
        for (int i = 0; i < 4; i++) {
            ah[i] = *(const bfrag8*)(Ahi + (wr * 64 + i * 16 + l15) * 64 + q16);
            bh[i] = *(const bfrag8*)(Bhi + (wc * 64 + i * 16 + l15) * 64 + q16);
        }
#pragma unroll
        for (int i = 0; i < 4; i++)
#pragma unroll
            for (int j = 0; j < 4; j++)
                acc[i][j] = __builtin_amdgcn_mfma_f32_16x16x32_bf16(ah[i], bh[j], acc[i][j], 0, 0, 0);
        __syncthreads();
    }
    const int col = lane & 15, qr = (lane >> 4) * 4;
#pragma unroll
    for (int i = 0; i < 4; i++)
#pragma unroll
        for (int j = 0; j < 4; j++)
#pragma unroll
            for (int r = 0; r < 4; r++) {
                int c = c0 + wr * 64 + 16 * i + qr + r;
                int mm = m0 + wc * 64 + 16 * j + col;
                float v = acc[i][j][r];
                if (kz == 0)
                    v += join_bf16(Yhi[(size_t)c * NSP + mm], Ylo[(size_t)c * NSP + mm]);
                atomicAdd(&Out[(size_t)c * NSP + mm], v);
            }
}

extern "C" void kernel_launch(void* const* d_in, const int* in_sizes, int n_in,
                              void* d_out, int out_size, void* d_ws, size_t ws_size,
                              hipStream_t stream) {
    const float* x = (const float*)d_in[0];
    float* out = (float*)d_out;

    // workspace layout (total 196 MB, same as R6):
    //   [0,128MB): S0|S1 (two 64MB fp32 score buffers, stage 2)
    //              aliased by X-prep region [0,96MB) (dead after k3)
    //   [128,192MB): Yhi|Ylo|YThi|YTlo (live to end)
    //              Pk (k1 partials, 32MB) aliases Yhi|Ylo (dead before k3)
    //   [192,196MB): Lg
    char* p = (char*)d_ws;
    const size_t SZ16 = (size_t)BATCH * CH * NSP * 2;  // 16 MB
    u16* XHi = (u16*)p;
    u16* XLo = (u16*)(p + SZ16);
    u16* XT2hi = (u16*)(p + 2 * SZ16);
    u16* XT2lo = (u16*)(p + 3 * SZ16);
    u16* XT1hi = (u16*)(p + 4 * SZ16);
    u16* XT1lo = (u16*)(p + 5 * SZ16);
    float* S = (float*)p;                      // S0 at 0, S1 at +64MB (contiguous)
    u16* Yhi = (u16*)(p + 8 * SZ16);           // 128MB
    u16* Ylo = (u16*)(p + 9 * SZ16);
    u16* YThi = (u16*)(p + 10 * SZ16);
    u16* YTlo = (u16*)(p + 11 * SZ16);
    float* Pk = (float*)(p + 8 * SZ16);        // aliases Yhi|Ylo (32MB)
    float* Lg = (float*)(p + 12 * SZ16);       // 4MB

    // Stage 1: channel attention
    k_prep_cn<<<dim3(NSP / 64, CH / 64, BATCH), 256, 0, stream>>>(x, XHi, XLo, XT1hi, XT1lo);
    k_prep_nc<<<dim3(NSP / 64, CH / 64, BATCH), 256, 0, stream>>>(x, XT2hi, XT2lo);
    k1_mfma<<<dim3(512), 256, 0, stream>>>(XHi, XLo, XT2hi, XT2lo, Pk);
    k_combine8<<<dim3((BATCH * CH * CH) / (4 * 256)), 256, 0, stream>>>(Pk, Lg);
    k_softmax_pack512<<<dim3(BATCH * CH), 256, 0, stream>>>(Lg);
    k3_mfma<<<dim3(NSP / 128, CH / 128, BATCH), 256, 0, stream>>>((const u16*)Lg, XT1hi, XT1lo, x,
                                                                  Yhi, Ylo);
    k_transpose_split<<<dim3(CH / 64, NSP / 64, BATCH), 256, 0, stream>>>(Yhi, Ylo, YThi, YTlo,
                                                                          CH, NSP);
    k_zero<<<dim3((BATCH * CH * NSP) / (4 * 256)), 256, 0, stream>>>(out);

    // Stage 2: positional attention, 2 batches per round
    const int TRI = (NSP / 128) * (NSP / 128 + 1) / 2;  // 528
    for (int round = 0; round < 2; round++) {
        const size_t b0 = (size_t)(2 * round);
        k4_mfma<<<dim3(TRI, 2), 256, 0, stream>>>(YThi + b0 * NSP * CH, YTlo + b0 * NSP * CH, S);
        k_softmax_pack<<<dim3(2 * NSP), 256, 0, stream>>>(S);
        k6_mfma<<<dim3(NSP / 128, CH / 128, 4), 256, 0, stream>>>(Yhi + b0 * CH * NSP,
                                                                  Ylo + b0 * CH * NSP,
                                                                  (const u16*)S,
                                                                  out + b0 * CH * NSP);
    }
}

// Round 8
// 494.878 us; speedup vs baseline: 5.8297x; 1.1197x over previous
//
#include <hip/hip_runtime.h>

#define BATCH 4
#define CH 512
#define NSP 4096   // 64*64 spatial

typedef __attribute__((ext_vector_type(8))) short bfrag8;  // 8 bf16 (4 VGPRs)
typedef __attribute__((ext_vector_type(4))) float f32x4;
typedef unsigned short u16;

#define AS1 __attribute__((address_space(1)))
#define AS3 __attribute__((address_space(3)))
__device__ __forceinline__ void gload16(const void* g, void* l) {
    __builtin_amdgcn_global_load_lds((const AS1 void*)g, (AS3 void*)l, 16, 0, 0);
}

__device__ __forceinline__ void split_bf16(float y, u16& h, u16& l) {
    unsigned int u = __float_as_uint(y);
    h = (u16)(u >> 16);
    float r = y - __uint_as_float(((unsigned int)h) << 16);
    l = (u16)(__float_as_uint(r) >> 16);
}
__device__ __forceinline__ float join_bf16(u16 h, u16 l) {
    return __uint_as_float(((unsigned int)h) << 16) + __uint_as_float(((unsigned int)l) << 16);
}

// ---------------------------------------------------------------------------
// prep 1: x [C][N] view -> XHi/XLo (same layout) + XT1 [n][c] (transpose)
// ---------------------------------------------------------------------------
__global__ __launch_bounds__(256) void k_prep_cn(const float* __restrict__ X,
                                                 u16* __restrict__ XHi,
                                                 u16* __restrict__ XLo,
                                                 u16* __restrict__ XT1hi,
                                                 u16* __restrict__ XT1lo) {
    __shared__ unsigned int t[64][65];
    const size_t boff = (size_t)blockIdx.z * CH * NSP;
    const int c0 = blockIdx.y * 64, n0 = blockIdx.x * 64;
    const int r = threadIdx.x >> 4, col4 = (threadIdx.x & 15) * 4;
#pragma unroll
    for (int it = 0; it < 4; it++) {
        int rl = r + it * 16;
        float4 v = *(const float4*)(X + boff + (size_t)(c0 + rl) * NSP + n0 + col4);
        ushort4 h, l;
        split_bf16(v.x, h.x, l.x);
        split_bf16(v.y, h.y, l.y);
        split_bf16(v.z, h.z, l.z);
        split_bf16(v.w, h.w, l.w);
        *(ushort4*)(XHi + boff + (size_t)(c0 + rl) * NSP + n0 + col4) = h;
        *(ushort4*)(XLo + boff + (size_t)(c0 + rl) * NSP + n0 + col4) = l;
        t[rl][col4 + 0] = ((unsigned int)h.x << 16) | l.x;
        t[rl][col4 + 1] = ((unsigned int)h.y << 16) | l.y;
        t[rl][col4 + 2] = ((unsigned int)h.z << 16) | l.z;
        t[rl][col4 + 3] = ((unsigned int)h.w << 16) | l.w;
    }
    __syncthreads();
#pragma unroll
    for (int it = 0; it < 4; it++) {
        int cl = r + it * 16;
        unsigned int p0 = t[col4 + 0][cl];
        unsigned int p1 = t[col4 + 1][cl];
        unsigned int p2 = t[col4 + 2][cl];
        unsigned int p3 = t[col4 + 3][cl];
        ushort4 hv, lv;
        hv.x = p0 >> 16; hv.y = p1 >> 16; hv.z = p2 >> 16; hv.w = p3 >> 16;
        lv.x = p0 & 0xffff; lv.y = p1 & 0xffff; lv.z = p2 & 0xffff; lv.w = p3 & 0xffff;
        *(ushort4*)(XT1hi + boff + (size_t)(n0 + cl) * CH + c0 + col4) = hv;
        *(ushort4*)(XT1lo + boff + (size_t)(n0 + cl) * CH + c0 + col4) = lv;
    }
}

// prep 2: x [N][C] view -> XT2 [d][n] (transpose)
__global__ __launch_bounds__(256) void k_prep_nc(const float* __restrict__ X,
                                                 u16* __restrict__ XT2hi,
                                                 u16* __restrict__ XT2lo) {
    __shared__ unsigned int t[64][65];
    const size_t boff = (size_t)blockIdx.z * CH * NSP;
    const int n0 = blockIdx.x * 64, d0 = blockIdx.y * 64;
    const int r = threadIdx.x >> 4, col4 = (threadIdx.x & 15) * 4;
#pragma unroll
    for (int it = 0; it < 4; it++) {
        int rl = r + it * 16;
        float4 v = *(const float4*)(X + boff + (size_t)(n0 + rl) * CH + d0 + col4);
        ushort4 h, l;
        split_bf16(v.x, h.x, l.x);
        split_bf16(v.y, h.y, l.y);
        split_bf16(v.z, h.z, l.z);
        split_bf16(v.w, h.w, l.w);
        t[rl][col4 + 0] = ((unsigned int)h.x << 16) | l.x;
        t[rl][col4 + 1] = ((unsigned int)h.y << 16) | l.y;
        t[rl][col4 + 2] = ((unsigned int)h.z << 16) | l.z;
        t[rl][col4 + 3] = ((unsigned int)h.w << 16) | l.w;
    }
    __syncthreads();
#pragma unroll
    for (int it = 0; it < 4; it++) {
        int cl = r + it * 16;
        unsigned int p0 = t[col4 + 0][cl];
        unsigned int p1 = t[col4 + 1][cl];
        unsigned int p2 = t[col4 + 2][cl];
        unsigned int p3 = t[col4 + 3][cl];
        ushort4 hv, lv;
        hv.x = p0 >> 16; hv.y = p1 >> 16; hv.z = p2 >> 16; hv.w = p3 >> 16;
        lv.x = p0 & 0xffff; lv.y = p1 & 0xffff; lv.z = p2 & 0xffff; lv.w = p3 & 0xffff;
        *(ushort4*)(XT2hi + boff + (size_t)(d0 + cl) * NSP + n0 + col4) = hv;
        *(ushort4*)(XT2lo + boff + (size_t)(d0 + cl) * NSP + n0 + col4) = lv;
    }
}

// ---------------------------------------------------------------------------
// k1 MFMA split-K=8 with XCD swizzle; partials -> Pk (aliases Y region)
// ---------------------------------------------------------------------------
__global__ __launch_bounds__(256, 2) void k1_mfma(const u16* __restrict__ XHi,
                                                  const u16* __restrict__ XLo,
                                                  const u16* __restrict__ XT2hi,
                                                  const u16* __restrict__ XT2lo,
                                                  float* __restrict__ Pk) {
    __shared__ __align__(16) char smem[32768];
    char* Ahi = smem;
    char* Alo = smem + 8192;
    char* Bhi = smem + 16384;
    char* Blo = smem + 24576;
    const int bid = blockIdx.x;
    const int xcd = bid & 7;
    const int i1 = bid >> 3;
    const int group = xcd * 4 + (i1 >> 4);
    const int b = group >> 3, kz = group & 7;
    const int tile = i1 & 15;
    const int c0 = (tile >> 2) * 128, d0 = (tile & 3) * 128;
    const size_t boff = (size_t)b * CH * NSP;
    const int tid = threadIdx.x, lane = tid & 63, w = tid >> 6;
    const int wr = w >> 1, wc = w & 1;
    const int rl = lane >> 2;
    const int cb = (lane & 3) * 8;
    f32x4 acc[4][4];
#pragma unroll
    for (int i = 0; i < 4; i++)
#pragma unroll
        for (int j = 0; j < 4; j++) acc[i][j] = (f32x4){0.f, 0.f, 0.f, 0.f};

    const int kbeg = kz * 512, kend = kbeg + 512;
    for (int k0 = kbeg; k0 < kend; k0 += 32) {
#pragma unroll
        for (int s = 0; s < 2; s++) {
            int idx = w * 2 + s;
            int row = 16 * idx + rl;
            gload16(XHi + boff + (size_t)(c0 + row) * NSP + k0 + cb, Ahi + idx * 1024);
            gload16(XLo + boff + (size_t)(c0 + row) * NSP + k0 + cb, Alo + idx * 1024);
            gload16(XT2hi + boff + (size_t)(d0 + row) * NSP + k0 + cb, Bhi + idx * 1024);
            gload16(XT2lo + boff + (size_t)(d0 + row) * NSP + k0 + cb, Blo + idx * 1024);
        }
        __syncthreads();
        bfrag8 ah[4], al[4], bh[4], bl[4];
        const int q16 = (lane >> 4) * 16;
        const int l15 = (lane & 15);
#pragma unroll
        for (int i = 0; i < 4; i++) {
            int offa = (wr * 64 + i * 16 + l15) * 64 + q16;
            ah[i] = *(const bfrag8*)(Ahi + offa);
            al[i] = *(const bfrag8*)(Alo + offa);
            int offb = (wc * 64 + i * 16 + l15) * 64 + q16;
            bh[i] = *(const bfrag8*)(Bhi + offb);
            bl[i] = *(const bfrag8*)(Blo + offb);
        }
#pragma unroll
        for (int i = 0; i < 4; i++)
#pragma unroll
            for (int j = 0; j < 4; j++) {
                acc[i][j] = __builtin_amdgcn_mfma_f32_16x16x32_bf16(ah[i], bh[j], acc[i][j], 0, 0, 0);
                acc[i][j] = __builtin_amdgcn_mfma_f32_16x16x32_bf16(ah[i], bl[j], acc[i][j], 0, 0, 0);
                acc[i][j] = __builtin_amdgcn_mfma_f32_16x16x32_bf16(al[i], bh[j], acc[i][j], 0, 0, 0);
            }
        __syncthreads();
    }
    float* Lb = Pk + (size_t)kz * BATCH * CH * CH + (size_t)b * CH * CH;
    const int col = lane & 15, qr = (lane >> 4) * 4;
#pragma unroll
    for (int i = 0; i < 4; i++)
#pragma unroll
        for (int j = 0; j < 4; j++)
#pragma unroll
            for (int r = 0; r < 4; r++)
                Lb[(size_t)(c0 + wr * 64 + 16 * i + qr + r) * CH + d0 + wc * 64 + 16 * j + col] =
                    acc[i][j][r];
}

__global__ __launch_bounds__(256) void k_combine8(const float* __restrict__ Pk,
                                                  float* __restrict__ Lg) {
    const size_t MM = (size_t)BATCH * CH * CH;
    size_t i = ((size_t)blockIdx.x * 256 + threadIdx.x) * 4;
    float4 s = *(const float4*)(Pk + i);
#pragma unroll
    for (int z = 1; z < 8; z++) {
        float4 v = *(const float4*)(Pk + z * MM + i);
        s.x += v.x; s.y += v.y; s.z += v.z; s.w += v.w;
    }
    *(float4*)(Lg + i) = s;
}

// softmax rows of 512 -> packed hi/lo bf16 in place
__global__ __launch_bounds__(256) void k_softmax_pack512(float* __restrict__ Lg) {
    __shared__ float buf[512];
    __shared__ float red[256];
    const int tid = threadIdx.x;
    float* row = Lg + (size_t)blockIdx.x * 512;
    float2 v = *(const float2*)(row + tid * 2);
    buf[tid * 2] = v.x;
    buf[tid * 2 + 1] = v.y;
    red[tid] = fmaxf(v.x, v.y);
    __syncthreads();
    for (int s = 128; s > 0; s >>= 1) {
        if (tid < s) red[tid] = fmaxf(red[tid], red[tid + s]);
        __syncthreads();
    }
    float m = red[0];
    __syncthreads();
    float e0 = __expf(buf[tid * 2] - m), e1 = __expf(buf[tid * 2 + 1] - m);
    buf[tid * 2] = e0;
    buf[tid * 2 + 1] = e1;
    red[tid] = e0 + e1;
    __syncthreads();
    for (int s = 128; s > 0; s >>= 1) {
        if (tid < s) red[tid] += red[tid + s];
        __syncthreads();
    }
    float inv = 1.0f / red[0];
    u16* u = (u16*)row;
    u16 h0, l0, h1, l1;
    split_bf16(buf[tid * 2] * inv, h0, l0);
    split_bf16(buf[tid * 2 + 1] * inv, h1, l1);
    __syncthreads();
    u[tid * 2] = h0;
    u[tid * 2 + 1] = h1;
    u[512 + tid * 2] = l0;
    u[512 + tid * 2 + 1] = l1;
}

// ---------------------------------------------------------------------------
// k3 MFMA (3-term): Y = A*pq + x. Epilogue writes Yhi/Ylo AND the transposed
// YT [n][c] via per-wave padded-LDS tiles (k4-mirror pattern) — fused, no
// separate transpose kernel.
// ---------------------------------------------------------------------------
__global__ __launch_bounds__(256, 2) void k3_mfma(const u16* __restrict__ Lu,
                                                  const u16* __restrict__ XT1hi,
                                                  const u16* __restrict__ XT1lo,
                                                  const float* __restrict__ X,
                                                  u16* __restrict__ Yhi,
                                                  u16* __restrict__ Ylo,
                                                  u16* __restrict__ YThi,
                                                  u16* __restrict__ YTlo) {
    __shared__ __align__(16) char smem[33280];  // 32KB staging; 2x(64x65 u32) transpose
    char* Ahi = smem;
    char* Alo = smem + 8192;
    char* Bhi = smem + 16384;
    char* Blo = smem + 24576;
    const int b = blockIdx.z;
    const u16* Au = Lu + (size_t)b * CH * 1024;
    const size_t boff = (size_t)b * CH * NSP;
    const float* Xb = X + boff;
    const int tid = threadIdx.x, lane = tid & 63, w = tid >> 6;
    const int wr = w >> 1, wc = w & 1;
    const int c0 = blockIdx.y * 128, n0 = blockIdx.x * 128;
    const int rl = lane >> 2;
    const int cb = (lane & 3) * 8;
    f32x4 acc[4][4];
#pragma unroll
    for (int i = 0; i < 4; i++)
#pragma unroll
        for (int j = 0; j < 4; j++) acc[i][j] = (f32x4){0.f, 0.f, 0.f, 0.f};

    for (int k0 = 0; k0 < CH; k0 += 32) {
#pragma unroll
        for (int s = 0; s < 2; s++) {
            int idx = w * 2 + s;
            int row = 16 * idx + rl;
            gload16(Au + (size_t)(c0 + row) * 1024 + k0 + cb, Ahi + idx * 1024);
            gload16(Au + (size_t)(c0 + row) * 1024 + 512 + k0 + cb, Alo + idx * 1024);
            gload16(XT1hi + boff + (size_t)(n0 + row) * CH + k0 + cb, Bhi + idx * 1024);
            gload16(XT1lo + boff + (size_t)(n0 + row) * CH + k0 + cb, Blo + idx * 1024);
        }
        __syncthreads();
        bfrag8 ah[4], al[4], bh[4], bl[4];
        const int q16 = (lane >> 4) * 16;
        const int l15 = (lane & 15);
#pragma unroll
        for (int i = 0; i < 4; i++) {
            int offa = (wr * 64 + i * 16 + l15) * 64 + q16;
            ah[i] = *(const bfrag8*)(Ahi + offa);
            al[i] = *(const bfrag8*)(Alo + offa);
            int offb = (wc * 64 + i * 16 + l15) * 64 + q16;
            bh[i] = *(const bfrag8*)(Bhi + offb);
            bl[i] = *(const bfrag8*)(Blo + offb);
        }
#pragma unroll
        for (int i = 0; i < 4; i++)
#pragma unroll
            for (int j = 0; j < 4; j++) {
                acc[i][j] = __builtin_amdgcn_mfma_f32_16x16x32_bf16(ah[i], bh[j], acc[i][j], 0, 0, 0);
                acc[i][j] = __builtin_amdgcn_mfma_f32_16x16x32_bf16(ah[i], bl[j], acc[i][j], 0, 0, 0);
                acc[i][j] = __builtin_amdgcn_mfma_f32_16x16x32_bf16(al[i], bh[j], acc[i][j], 0, 0, 0);
            }
        __syncthreads();
    }
    u16* Yhb = Yhi + boff;
    u16* Ylb = Ylo + boff;
    u16* YThb = YThi + boff;  // [n][c], same per-batch element count
    u16* YTlb = YTlo + boff;
    const int col = lane & 15, qr = (lane >> 4) * 4;
    unsigned int* Tb = (unsigned int*)smem;  // two 64x65 u32 wave-tiles
#pragma unroll
    for (int round = 0; round < 2; round++) {
        if (wr == round) {
            unsigned int* T = Tb + wc * 4160;
#pragma unroll
            for (int i = 0; i < 4; i++)
#pragma unroll
                for (int j = 0; j < 4; j++)
#pragma unroll
                    for (int r = 0; r < 4; r++) {
                        int cl = 16 * i + qr + r;       // c within wave tile
                        int nl = 16 * j + col;          // n within wave tile
                        int c = c0 + wr * 64 + cl;
                        int n = n0 + wc * 64 + nl;
                        float v = acc[i][j][r] + Xb[(size_t)c * NSP + n];
                        u16 h, l;
                        split_bf16(v, h, l);
                        Yhb[(size_t)c * NSP + n] = h;
                        Ylb[(size_t)c * NSP + n] = l;
                        T[nl * 65 + cl] = ((unsigned int)h << 16) | l;
                    }
        }
        __syncthreads();
        if (wr == round) {
            unsigned int* T = Tb + wc * 4160;
            const int cl = (lane & 15) * 4;
#pragma unroll
            for (int rep = 0; rep < 16; rep++) {
                int nq = rep * 4 + (lane >> 4);
                unsigned int p0 = T[nq * 65 + cl];
                unsigned int p1 = T[nq * 65 + cl + 1];
                unsigned int p2 = T[nq * 65 + cl + 2];
                unsigned int p3 = T[nq * 65 + cl + 3];
                ushort4 hv, lv;
                hv.x = p0 >> 16; hv.y = p1 >> 16; hv.z = p2 >> 16; hv.w = p3 >> 16;
                lv.x = p0 & 0xffff; lv.y = p1 & 0xffff; lv.z = p2 & 0xffff; lv.w = p3 & 0xffff;
                size_t o = (size_t)(n0 + wc * 64 + nq) * CH + c0 + wr * 64 + cl;
                *(ushort4*)(YThb + o) = hv;
                *(ushort4*)(YTlb + o) = lv;
            }
        }
        __syncthreads();
    }
}

// ---------------------------------------------------------------------------
// k4 MFMA symmetric (3-term), 2 batches per launch (blockIdx.y = rb).
// ---------------------------------------------------------------------------
__global__ __launch_bounds__(256, 2) void k4_mfma(const u16* __restrict__ YThi0,
                                                  const u16* __restrict__ YTlo0,
                                                  float* __restrict__ S0) {
    __shared__ __align__(16) char smem[34816];
    char* Ahi = smem;
    char* Alo = smem + 8192;
    char* Bhi = smem + 16384;
    char* Blo = smem + 24576;
    const int tid = threadIdx.x, lane = tid & 63, w = tid >> 6;
    const int wr = w >> 1, wc = w & 1;
    const int rb = blockIdx.y;
    const u16* YThi = YThi0 + (size_t)rb * NSP * CH;
    const u16* YTlo = YTlo0 + (size_t)rb * NSP * CH;
    float* S = S0 + (size_t)rb * NSP * NSP;
    int idx = blockIdx.x;
    int bi = (int)((sqrtf(8.f * (float)idx + 1.f) - 1.f) * 0.5f);
    while ((bi + 1) * (bi + 2) / 2 <= idx) bi++;
    while (bi * (bi + 1) / 2 > idx) bi--;
    int bj = idx - bi * (bi + 1) / 2;
    const int n0 = bi * 128, m0 = bj * 128;
    const bool diag = (bi == bj);
    const int rl = lane >> 2;
    const int cb = (lane & 3) * 8;
    f32x4 acc[4][4];
#pragma unroll
    for (int i = 0; i < 4; i++)
#pragma unroll
        for (int j = 0; j < 4; j++) acc[i][j] = (f32x4){0.f, 0.f, 0.f, 0.f};

    for (int k0 = 0; k0 < CH; k0 += 32) {
#pragma unroll
        for (int s = 0; s < 2; s++) {
            int i2 = w * 2 + s;
            int row = 16 * i2 + rl;
            gload16(YThi + (size_t)(n0 + row) * CH + k0 + cb, Ahi + i2 * 1024);
            gload16(YTlo + (size_t)(n0 + row) * CH + k0 + cb, Alo + i2 * 1024);
            gload16(YThi + (size_t)(m0 + row) * CH + k0 + cb, Bhi + i2 * 1024);
            gload16(YTlo + (size_t)(m0 + row) * CH + k0 + cb, Blo + i2 * 1024);
        }
        __syncthreads();
        bfrag8 ah[4], al[4], bh[4], bl[4];
        const int q16 = (lane >> 4) * 16;
        const int l15 = (lane & 15);
#pragma unroll
        for (int i = 0; i < 4; i++) {
            int offa = (wr * 64 + i * 16 + l15) * 64 + q16;
            ah[i] = *(const bfrag8*)(Ahi + offa);
            al[i] = *(const bfrag8*)(Alo + offa);
            int offb = (wc * 64 + i * 16 + l15) * 64 + q16;
            bh[i] = *(const bfrag8*)(Bhi + offb);
            bl[i] = *(const bfrag8*)(Blo + offb);
        }
#pragma unroll
        for (int i = 0; i < 4; i++)
#pragma unroll
            for (int j = 0; j < 4; j++) {
                acc[i][j] = __builtin_amdgcn_mfma_f32_16x16x32_bf16(ah[i], bh[j], acc[i][j], 0, 0, 0);
                acc[i][j] = __builtin_amdgcn_mfma_f32_16x16x32_bf16(ah[i], bl[j], acc[i][j], 0, 0, 0);
                acc[i][j] = __builtin_amdgcn_mfma_f32_16x16x32_bf16(al[i], bh[j], acc[i][j], 0, 0, 0);
            }
        __syncthreads();
    }
    const int col = lane & 15, qr = (lane >> 4) * 4;
#pragma unroll
    for (int i = 0; i < 4; i++)
#pragma unroll
        for (int j = 0; j < 4; j++)
#pragma unroll
            for (int r = 0; r < 4; r++)
                S[(size_t)(n0 + wr * 64 + 16 * i + qr + r) * NSP + m0 + wc * 64 + 16 * j + col] =
                    acc[i][j][r];
    if (!diag) {
        float* Tbase = (float*)smem;
#pragma unroll
        for (int round = 0; round < 2; round++) {
            if (wr == round) {
                float* T = Tbase + wc * (64 * 68);
#pragma unroll
                for (int i = 0; i < 4; i++)
#pragma unroll
                    for (int j = 0; j < 4; j++)
#pragma unroll
                        for (int r = 0; r < 4; r++)
                            T[(16 * j + col) * 68 + 16 * i + qr + r] = acc[i][j][r];
            }
            __syncthreads();
            if (wr == round) {
                float* T = Tbase + wc * (64 * 68);
                const int rq = (lane & 15) * 4;
#pragma unroll
                for (int rep = 0; rep < 16; rep++) {
                    int cq = rep * 4 + (lane >> 4);
                    float4 v = *(const float4*)(T + cq * 68 + rq);
                    *(float4*)(S + (size_t)(m0 + wc * 64 + cq) * NSP + n0 + wr * 64 + rq) = v;
                }
            }
            __syncthreads();
        }
    }
}

// softmax rows of 4096 over contiguous S0|S1 (grid 8192); writes hi plane only
__global__ __launch_bounds__(256) void k_softmax_pack(float* __restrict__ S) {
    __shared__ float buf[4096];
    __shared__ float red[256];
    const int tid = threadIdx.x;
    float* row = S + (size_t)blockIdx.x * NSP;
    float m = -INFINITY;
#pragma unroll
    for (int it = 0; it < 4; it++) {
        int i = (tid + it * 256) * 4;
        float4 v = *(const float4*)(row + i);
        buf[i] = v.x; buf[i + 1] = v.y; buf[i + 2] = v.z; buf[i + 3] = v.w;
        m = fmaxf(m, fmaxf(fmaxf(v.x, v.y), fmaxf(v.z, v.w)));
    }
    red[tid] = m;
    __syncthreads();
    for (int s = 128; s > 0; s >>= 1) {
        if (tid < s) red[tid] = fmaxf(red[tid], red[tid + s]);
        __syncthreads();
    }
    m = red[0];
    __syncthreads();
    float sum = 0.f;
#pragma unroll
    for (int it = 0; it < 4; it++) {
        int i = (tid + it * 256) * 4;
        float e0 = __expf(buf[i] - m), e1 = __expf(buf[i + 1] - m);
        float e2 = __expf(buf[i + 2] - m), e3 = __expf(buf[i + 3] - m);
        buf[i] = e0; buf[i + 1] = e1; buf[i + 2] = e2; buf[i + 3] = e3;
        sum += e0 + e1 + e2 + e3;
    }
    red[tid] = sum;
    __syncthreads();
    for (int s = 128; s > 0; s >>= 1) {
        if (tid < s) red[tid] += red[tid + s];
        __syncthreads();
    }
    float inv = 1.0f / red[0];
    u16* u = (u16*)row;
#pragma unroll
    for (int it = 0; it < 4; it++) {
        int i = (tid + it * 256) * 4;
        ushort4 hv;
        hv.x = (u16)(__float_as_uint(buf[i] * inv) >> 16);
        hv.y = (u16)(__float_as_uint(buf[i + 1] * inv) >> 16);
        hv.z = (u16)(__float_as_uint(buf[i + 2] * inv) >> 16);
        hv.w = (u16)(__float_as_uint(buf[i + 3] * inv) >> 16);
        *(ushort4*)(u + i) = hv;
    }
}

// ---------------------------------------------------------------------------
// k6 MFMA 1-term, split-K=2, 2 batches/launch. NO atomics:
//   kz==0 -> Out = acc + residual (plain store)
//   kz==1 -> Ppart (per-round scratch in dead YT region)
// ---------------------------------------------------------------------------
__global__ __launch_bounds__(256, 2) void k6_mfma(const u16* __restrict__ Yhi0,
                                                  const u16* __restrict__ Ylo0,
                                                  const u16* __restrict__ Su,
                                                  float* __restrict__ Out0,
                                                  float* __restrict__ Pp0,
                                                  float* __restrict__ Pp1) {
    __shared__ __align__(16) char smem[16384];
    char* Ahi = smem;
    char* Bhi = smem + 8192;
    const int tid = threadIdx.x, lane = tid & 63, w = tid >> 6;
    const int wr = w >> 1, wc = w & 1;
    const int m0 = blockIdx.x * 128, c0 = blockIdx.y * 128;
    const int rb = blockIdx.z >> 1, kz = blockIdx.z & 1;
    const u16* Yhi = Yhi0 + (size_t)rb * CH * NSP;
    const u16* Ylo = Ylo0 + (size_t)rb * CH * NSP;
    const u16* Pu = Su + (size_t)rb * NSP * NSP * 2;  // S batch stride in u16 units
    float* Out = Out0 + (size_t)rb * CH * NSP;
    float* Ppart = rb ? Pp1 : Pp0;
    const int kb = kz * 2048;
    const int rl = lane >> 2;
    const int cb = (lane & 3) * 8;
    f32x4 acc[4][4];
#pragma unroll
    for (int i = 0; i < 4; i++)
#pragma unroll
        for (int j = 0; j < 4; j++) acc[i][j] = (f32x4){0.f, 0.f, 0.f, 0.f};

    for (int k0 = 0; k0 < 2048; k0 += 32) {
        const int kk = kb + k0;
#pragma unroll
        for (int s = 0; s < 2; s++) {
            int idx = w * 2 + s;
            int row = 16 * idx + rl;
            gload16(Yhi + (size_t)(c0 + row) * NSP + kk + cb, Ahi + idx * 1024);
            gload16(Pu + (size_t)(m0 + row) * 8192 + kk + cb, Bhi + idx * 1024);
        }
        __syncthreads();
        bfrag8 ah[4], bh[4];
        const int q16 = (lane >> 4) * 16;
        const int l15 = (lane & 15);
#pragma unroll
        for (int i = 0; i < 4; i++) {
            ah[i] = *(const bfrag8*)(Ahi + (wr * 64 + i * 16 + l15) * 64 + q16);
            bh[i] = *(const bfrag8*)(Bhi + (wc * 64 + i * 16 + l15) * 64 + q16);
        }
#pragma unroll
        for (int i = 0; i < 4; i++)
#pragma unroll
            for (int j = 0; j < 4; j++)
                acc[i][j] = __builtin_amdgcn_mfma_f32_16x16x32_bf16(ah[i], bh[j], acc[i][j], 0, 0, 0);
        __syncthreads();
    }
    const int col = lane & 15, qr = (lane >> 4) * 4;
    if (kz == 0) {
#pragma unroll
        for (int i = 0; i < 4; i++)
#pragma unroll
            for (int j = 0; j < 4; j++)
#pragma unroll
                for (int r = 0; r < 4; r++) {
                    int c = c0 + wr * 64 + 16 * i + qr + r;
                    int mm = m0 + wc * 64 + 16 * j + col;
                    Out[(size_t)c * NSP + mm] =
                        acc[i][j][r] +
                        join_bf16(Yhi[(size_t)c * NSP + mm], Ylo[(size_t)c * NSP + mm]);
                }
    } else {
#pragma unroll
        for (int i = 0; i < 4; i++)
#pragma unroll
            for (int j = 0; j < 4; j++)
#pragma unroll
                for (int r = 0; r < 4; r++) {
                    int c = c0 + wr * 64 + 16 * i + qr + r;
                    int mm = m0 + wc * 64 + 16 * j + col;
                    Ppart[(size_t)c * NSP + mm] = acc[i][j][r];
                }
    }
}

// out[b] += Ppart[b] for the round's 2 batches
__global__ __launch_bounds__(256) void k_fixup(float* __restrict__ Out0,
                                               const float* __restrict__ Pp0,
                                               const float* __restrict__ Pp1) {
    const size_t CN = (size_t)CH * NSP;
    const int b = blockIdx.y;
    const float* P = b ? Pp1 : Pp0;
    float* O = Out0 + (size_t)b * CN;
    size_t i = ((size_t)blockIdx.x * 256 + threadIdx.x) * 4;
    float4 o = *(const float4*)(O + i);
    float4 a = *(const float4*)(P + i);
    o.x += a.x; o.y += a.y; o.z += a.z; o.w += a.w;
    *(float4*)(O + i) = o;
}

extern "C" void kernel_launch(void* const* d_in, const int* in_sizes, int n_in,
                              void* d_out, int out_size, void* d_ws, size_t ws_size,
                              hipStream_t stream) {
    const float* x = (const float*)d_in[0];
    float* out = (float*)d_out;

    // workspace layout (196 MB):
    //   [0,128MB): S0|S1 fp32 score buffers; aliased by X-prep [0,96MB) (dead after k3)
    //   [128,192MB): Yhi|Ylo|YThi|YTlo (YT per-batch 4MB slices)
    //       Pk (k1 partials, 32MB) aliases Yhi|Ylo (dead before k3)
    //       k6 round-r partials alias the YT slices of round r's batches (dead after k4)
    //   [192,196MB): Lg
    char* p = (char*)d_ws;
    const size_t SZ16 = (size_t)BATCH * CH * NSP * 2;  // 16 MB
    const size_t HALF = SZ16 / 2;                      // 8 MB = CH*NSP*4
    u16* XHi = (u16*)p;
    u16* XLo = (u16*)(p + SZ16);
    u16* XT2hi = (u16*)(p + 2 * SZ16);
    u16* XT2lo = (u16*)(p + 3 * SZ16);
    u16* XT1hi = (u16*)(p + 4 * SZ16);
    u16* XT1lo = (u16*)(p + 5 * SZ16);
    float* S = (float*)p;
    u16* Yhi = (u16*)(p + 8 * SZ16);
    u16* Ylo = (u16*)(p + 9 * SZ16);
    u16* YThi = (u16*)(p + 10 * SZ16);
    u16* YTlo = (u16*)(p + 11 * SZ16);
    float* Pk = (float*)(p + 8 * SZ16);
    float* Lg = (float*)(p + 12 * SZ16);

    // Stage 1: channel attention
    k_prep_cn<<<dim3(NSP / 64, CH / 64, BATCH), 256, 0, stream>>>(x, XHi, XLo, XT1hi, XT1lo);
    k_prep_nc<<<dim3(NSP / 64, CH / 64, BATCH), 256, 0, stream>>>(x, XT2hi, XT2lo);
    k1_mfma<<<dim3(512), 256, 0, stream>>>(XHi, XLo, XT2hi, XT2lo, Pk);
    k_combine8<<<dim3((BATCH * CH * CH) / (4 * 256)), 256, 0, stream>>>(Pk, Lg);
    k_softmax_pack512<<<dim3(BATCH * CH), 256, 0, stream>>>(Lg);
    k3_mfma<<<dim3(NSP / 128, CH / 128, BATCH), 256, 0, stream>>>((const u16*)Lg, XT1hi, XT1lo, x,
                                                                  Yhi, Ylo, YThi, YTlo);

    // Stage 2: positional attention, 2 batches per round
    const int TRI = (NSP / 128) * (NSP / 128 + 1) / 2;  // 528
    for (int round = 0; round < 2; round++) {
        const size_t b0 = (size_t)(2 * round);
        // round r's k6 split-K partials live in the YT slices of batches 2r,2r+1
        // (each YT plane is 4MB/batch; the two slices per plane give 8MB = one
        // batch's fp32 partial). Dead after this round's k4.
        float* Pp0 = (float*)((char*)YThi + round * HALF);
        float* Pp1 = (float*)((char*)YTlo + round * HALF);
        k4_mfma<<<dim3(TRI, 2), 256, 0, stream>>>(YThi + b0 * NSP * CH, YTlo + b0 * NSP * CH, S);
        k_softmax_pack<<<dim3(2 * NSP), 256, 0, stream>>>(S);
        k6_mfma<<<dim3(NSP / 128, CH / 128, 4), 256, 0, stream>>>(Yhi + b0 * CH * NSP,
                                                                  Ylo + b0 * CH * NSP,
                                                                  (const u16*)S,
                                                                  out + b0 * CH * NSP, Pp0, Pp1);
        k_fixup<<<dim3((CH * NSP) / (4 * 256), 2), 256, 0, stream>>>(out + b0 * CH * NSP, Pp0, Pp1);
    }
}